// Round 8
// baseline (202.336 us; speedup 1.0000x reference)
//
#include <hip/hip_runtime.h>
#include <math.h>

typedef unsigned short u16;
typedef unsigned int u32;
typedef __bf16 bfrag8 __attribute__((ext_vector_type(8)));
typedef float f32x4 __attribute__((ext_vector_type(4)));

#define B_ 2
#define T_ 2048
#define H_ 16
#define D_ 64
#define C_ 1024
#define NQKV_ 3072

#define MFMA_BF16(a, b, c) __builtin_amdgcn_mfma_f32_16x16x32_bf16((a), (b), (c), 0, 0, 0)

__device__ __forceinline__ u16 f2bf(float f) {
  u32 u = __builtin_bit_cast(u32, f);
  u += 0x7fffu + ((u >> 16) & 1u);  // RNE
  return (u16)(u >> 16);
}

// async global->LDS, 16B/lane; lds dest = wave-uniform base + lane*16
__device__ __forceinline__ void load_lds16(const u16* gp, u16* lp) {
  __builtin_amdgcn_global_load_lds(
      (const __attribute__((address_space(1))) u32*)(const void*)gp,
      (__attribute__((address_space(3))) u32*)(void*)lp, 16, 0, 0);
}

// -------- fused prep: convert x (f32->bf16) + transpose both weights. --------
__global__ __launch_bounds__(256) void prep(const float* __restrict__ x,
                                            u16* __restrict__ xb,
                                            const float* __restrict__ wqkv,
                                            u16* __restrict__ wqkvT,
                                            const float* __restrict__ wproj,
                                            u16* __restrict__ wprojT) {
  int bid = blockIdx.x;
  int tid = threadIdx.x;
  __shared__ u16 tile[64][65];
  if (bid < 2048) {
    size_t i = ((size_t)bid * 256 + tid) * 8;
    const float* s = x + i;
    float4 a = *(const float4*)s, b = *(const float4*)(s + 4);
    union { uint4 v; u16 h[8]; } t;
    t.h[0] = f2bf(a.x); t.h[1] = f2bf(a.y); t.h[2] = f2bf(a.z); t.h[3] = f2bf(a.w);
    t.h[4] = f2bf(b.x); t.h[5] = f2bf(b.y); t.h[6] = f2bf(b.z); t.h[7] = f2bf(b.w);
    *(uint4*)(xb + i) = t.v;
    return;
  }
  const float* src;
  u16* dst;
  int N, bx, by;
  if (bid < 2816) {
    int rel = bid - 2048;
    src = wqkv; dst = wqkvT; N = NQKV_;
    bx = (rel % 48) * 64; by = (rel / 48) * 64;
  } else {
    int rel = bid - 2816;
    src = wproj; dst = wprojT; N = C_;
    bx = (rel & 15) * 64; by = (rel >> 4) * 64;
  }
  for (int idx = tid; idx < 4096; idx += 256) {
    int r = idx >> 6, c = idx & 63;
    tile[r][c] = f2bf(src[(size_t)(by + r) * N + bx + c]);
  }
  __syncthreads();
  for (int idx = tid; idx < 4096; idx += 256) {
    int r = idx >> 6, c = idx & 63;
    dst[(size_t)(bx + r) * C_ + by + c] = tile[c][r];
  }
}

// -------- GEMM 1: qkv = X(4096x1024)bf16 @ WT(3072x1024)bf16, RoPE(+q*1/8) epilogue.
// 128x128 tile, BK=64, A in dbuf chunk-XOR-swizzled LDS (r5-proven, conflicts=0).
// NEW r8: B-operand loaded DIRECTLY from global (L2-resident 256KB panel, 64B-segment
// coalesced) -> LDS pipe traffic halved (was ~60% busy: 128KB rd + 64KB wr /CU/iter),
// Bs deleted -> LDS 64->32KB -> 3 blocks/CU, grid 768 = exactly 3 full rounds. --------
__global__ __launch_bounds__(256, 3) void gemm_qkv_rope(const u16* __restrict__ X,
                                                        const u16* __restrict__ WT,
                                                        u16* __restrict__ qb,
                                                        u16* __restrict__ kb,
                                                        u16* __restrict__ vtb) {
  const int K = C_;
  __shared__ __align__(16) u16 As[2][128 * 64];  // 32 KB total
  int tid = threadIdx.x;
  int lane = tid & 63, wave = tid >> 6;
  int quad = lane >> 4, lr = lane & 15;
  int m0 = blockIdx.y * 128, n0 = blockIdx.x * 128;
  int wrow = (wave >> 1) * 64, wcol = (wave & 1) * 64;
  int r0 = wave * 32;  // this wave's staging row base (32 rows per wave)
  int srow = lane >> 3;
  int schunk = (lane & 7) ^ srow;  // pre-swizzled global source chunk

  // read-side swizzled chunk offsets (u16 units): logical chunk (ks*4+quad) ^ (row&7)
  int koff0 = ((quad ^ (lr & 7)) << 3);
  int koff1 = (((4 | quad) ^ (lr & 7)) << 3);

  f32x4 zero = {0.f, 0.f, 0.f, 0.f};
  f32x4 acc[4][4];
#pragma unroll
  for (int i = 0; i < 4; i++)
#pragma unroll
    for (int j = 0; j < 4; j++) acc[i][j] = zero;

  const u16* ga = X + (size_t)(m0 + r0 + srow) * K + schunk * 8;
  // B direct-load base: row n0+wcol+lr (+j*16), 16B chunk at quad*8 (+ks*32)
  const u16* gB = WT + (size_t)(n0 + wcol + lr) * K + quad * 8;

  // prologue: stage A tile 0 (4 loads/thread)
#pragma unroll
  for (int l = 0; l < 4; l++)
    load_lds16(ga + (size_t)(l * 8) * K, &As[0][(r0 + l * 8) * 64]);

  int buf = 0;
  for (int k0 = 0; k0 < K; k0 += 64) {
    __syncthreads();  // drains tile-k0 A loads (issued one compute phase ago)
    if (k0 + 64 < K) {
#pragma unroll
      for (int l = 0; l < 4; l++)
        load_lds16(ga + (size_t)(l * 8) * K + k0 + 64, &As[buf ^ 1][(r0 + l * 8) * 64]);
    }
    // B fragments direct from global (L2-hit)
    bfrag8 bf[4][2];
#pragma unroll
    for (int j = 0; j < 4; j++) {
      const u16* br = gB + (size_t)(j * 16) * K + k0;
      bf[j][0] = *(const bfrag8*)(br);
      bf[j][1] = *(const bfrag8*)(br + 32);
    }
    // A fragments from swizzled LDS
    bfrag8 af[4][2];
#pragma unroll
    for (int i = 0; i < 4; i++) {
      const u16* ar = &As[buf][(wrow + i * 16 + lr) * 64];
      af[i][0] = *(const bfrag8*)(ar + koff0);
      af[i][1] = *(const bfrag8*)(ar + koff1);
    }
#pragma unroll
    for (int i = 0; i < 4; i++)
#pragma unroll
      for (int j = 0; j < 4; j++) {
        acc[i][j] = MFMA_BF16(af[i][0], bf[j][0], acc[i][j]);
        acc[i][j] = MFMA_BF16(af[i][1], bf[j][1], acc[i][j]);
      }
    buf ^= 1;
  }

  int colbase = n0 + wcol;
  int which = colbase >> 10;  // 0=q 1=k 2=v
  int h = (colbase & 1023) >> 6;
  if (which < 2) {
    u16* dst = which == 0 ? qb : kb;
    float sc0 = (which == 0) ? 0.125f : 1.0f;
    float fr0 = __expf(-0.28782313662425574f * (float)lr);        // ln(10000)/32
    float fr1 = __expf(-0.28782313662425574f * (float)(16 + lr));
#pragma unroll
    for (int i = 0; i < 4; i++) {
#pragma unroll
      for (int r = 0; r < 4; r++) {
        int m = m0 + wrow + i * 16 + quad * 4 + r;
        int b = m >> 11, tt = m & 2047;
        size_t base = ((size_t)(b * H_ + h) * T_ + tt) * D_;
        float sn, cs;
        __sincosf((float)tt * fr0, &sn, &cs);
        dst[base + lr] = f2bf((acc[i][0][r] * cs - acc[i][2][r] * sn) * sc0);
        dst[base + lr + 32] = f2bf((acc[i][0][r] * sn + acc[i][2][r] * cs) * sc0);
        __sincosf((float)tt * fr1, &sn, &cs);
        dst[base + 16 + lr] = f2bf((acc[i][1][r] * cs - acc[i][3][r] * sn) * sc0);
        dst[base + 48 + lr] = f2bf((acc[i][1][r] * sn + acc[i][3][r] * cs) * sc0);
      }
    }
  } else {
    // V: write transposed [bh][d][t]; lane holds 4 consecutive t per (i,j) -> 8B store
#pragma unroll
    for (int i = 0; i < 4; i++) {
      int mb = m0 + wrow + i * 16 + quad * 4;  // 4 consecutive t from here (same b)
      int b = mb >> 11, tt = mb & 2047;
      u16* vb = vtb + ((size_t)(b * H_ + h) * D_) * T_ + tt;
#pragma unroll
      for (int j = 0; j < 4; j++) {
        union { uint2 v; u16 hh[4]; } pk;
#pragma unroll
        for (int r = 0; r < 4; r++) pk.hh[r] = f2bf(acc[i][j][r]);
        *(uint2*)(vb + (size_t)(j * 16 + lr) * T_) = pk.v;
      }
    }
  }
}

// -------- attention: causal, S^T formulation, q-tile 128 (8 waves, 512 thr,
// 16 q-rows/wave), kv-tile 64, dbuf + single barrier/iter, heavy-first blocks,
// XOR-swizzled K/V LDS. (r7 exact, FROZEN) ----
__global__ __launch_bounds__(512) void attn_k(const u16* __restrict__ qb,
                                              const u16* __restrict__ kb,
                                              const u16* __restrict__ vtb,
                                              u16* __restrict__ ob) {
  __shared__ __align__(16) u16 Ks[2][64 * 64];   // [t][chunk^t&7]  8 KB each
  __shared__ __align__(16) u16 Vt[2][64 * 64];   // [d][chunk^d&7]
  __shared__ __align__(16) u16 Pst[8][16 * 72];  // per-wave P [q=16][t=64 +pad]
  int tid = threadIdx.x;
  int lane = tid & 63, wave = tid >> 6;
  int quad = lane >> 4, lr = lane & 15;
  int i = blockIdx.x;
  int bq = 15 - (i >> 5);  // heavy blocks dispatched first (16 q-blocks of 128)
  int bh = i & 31;
  int b = bh >> 4, h = bh & 15;
  const u16* Q = qb + (size_t)bh * T_ * D_;
  const u16* Kp = kb + (size_t)bh * T_ * D_;
  const u16* Vp = vtb + (size_t)bh * D_ * T_;
  int qr0 = bq * 128 + wave * 16;  // this wave's q-row base
  int r0v = wave * 8;              // staging row base (8 rows/wave)
  int sr = lane >> 3;
  int sc = (((lane & 7) ^ sr) * 8);  // XOR-swizzled staging column

  // read-side swizzled chunk offsets (u16 units), constant per lane
  int koff0 = ((quad ^ (lr & 7)) << 3);
  int koff1 = (((4 | quad) ^ (lr & 7)) << 3);

  // Q fragment as MFMA B-operand: B[n=q][k=d] (from global, unswizzled)
  bfrag8 qf[2];
#pragma unroll
  for (int ks = 0; ks < 2; ks++)
    qf[ks] = *(const bfrag8*)(Q + (size_t)(qr0 + lr) * D_ + ks * 32 + quad * 8);

  f32x4 zero = {0.f, 0.f, 0.f, 0.f};
  f32x4 o[4];
#pragma unroll
  for (int nn = 0; nn < 4; nn++) o[nn] = zero;
  float psum = 0.f;

  const u16* gk = Kp + (size_t)(r0v + sr) * D_ + sc;
  const u16* gv = Vp + (size_t)(r0v + sr) * T_ + sc;
  int niter = 2 * bq + 2;                // kv tiles covering bq*128+128 rows
  int wlast = 2 * bq + (wave >> 2);      // this wave's causal last tile
  int qloc = (wave & 3) * 16 + lr;       // q-pos within last tile

  load_lds16(gk, &Ks[0][r0v * 64]);
  load_lds16(gv, &Vt[0][r0v * 64]);

  int buf = 0;
  for (int it = 0; it < niter; it++) {
    __syncthreads();  // drains loads for tile `it` (issued one compute-phase ago)
    if (it + 1 < niter) {
      int tkn = (it + 1) * 64;
      load_lds16(gk + (size_t)tkn * D_, &Ks[buf ^ 1][r0v * 64]);
      load_lds16(gv + tkn, &Vt[buf ^ 1][r0v * 64]);
    }
    if (it <= wlast) {  // wave-uniform: waves past causal region idle (barriers kept)
      const u16* ks_ = Ks[buf];
      const u16* vt_ = Vt[buf];

      // S^T = K Q^T : 64 kv-rows x 16 q-cols (A=K-frag swizzled, B=Q-frag)
      f32x4 s[4];
#pragma unroll
      for (int j = 0; j < 4; j++) s[j] = zero;
#pragma unroll
      for (int j = 0; j < 4; j++) {
        bfrag8 kf0 = *(const bfrag8*)&ks_[(j * 16 + lr) * 64 + koff0];
        bfrag8 kf1 = *(const bfrag8*)&ks_[(j * 16 + lr) * 64 + koff1];
        s[j] = MFMA_BF16(kf0, qf[0], s[j]);
        s[j] = MFMA_BF16(kf1, qf[1], s[j]);
      }

      // exp + pack pairs (RNE-ish) + ds_write_b64 to Pst[q][t]
      bool edge = (it == wlast);  // wave-uniform
#pragma unroll
      for (int j = 0; j < 4; j++) {
        float p[4];
#pragma unroll
        for (int r = 0; r < 4; r++) {
          float e = __expf(s[j][r]);
          if (edge) {
            int kvloc = j * 16 + quad * 4 + r;
            e = (kvloc <= qloc) ? e : 0.f;
          }
          p[r] = e;
          psum += e;
        }
        u32 u0 = __builtin_bit_cast(u32, p[0]) + 0x8000u;
        u32 u1 = __builtin_bit_cast(u32, p[1]) + 0x8000u;
        u32 u2 = __builtin_bit_cast(u32, p[2]) + 0x8000u;
        u32 u3 = __builtin_bit_cast(u32, p[3]) + 0x8000u;
        uint2 pk;
        pk.x = (u0 >> 16) | (u1 & 0xffff0000u);
        pk.y = (u2 >> 16) | (u3 & 0xffff0000u);
        *(uint2*)&Pst[wave][lr * 72 + j * 16 + quad * 4] = pk;
      }

      // O += P V : A = P[q][t] (b128 from Pst), B = V^T[d][t] (swizzled)
#pragma unroll
      for (int ks = 0; ks < 2; ks++) {
        bfrag8 pf = *(const bfrag8*)&Pst[wave][lr * 72 + ks * 32 + quad * 8];
        int ko = ks ? koff1 : koff0;
#pragma unroll
        for (int nn = 0; nn < 4; nn++) {
          bfrag8 vf = *(const bfrag8*)&vt_[(nn * 16 + lr) * 64 + ko];
          o[nn] = MFMA_BF16(pf, vf, o[nn]);
        }
      }
    }
    buf ^= 1;
  }

  // total row-sum: reduce over the 4 quads
  float l = psum;
  l += __shfl_xor(l, 16, 64);
  l += __shfl_xor(l, 32, 64);
  float linv = 1.0f / l;

#pragma unroll
  for (int r = 0; r < 4; r++) {
    float lrec = __shfl(linv, quad * 4 + r, 64);
    int row = qr0 + quad * 4 + r;
#pragma unroll
    for (int nn = 0; nn < 4; nn++)
      ob[(size_t)(b * T_ + row) * C_ + h * 64 + nn * 16 + lr] = f2bf(o[nn][r] * lrec);
  }
}

// -------- GEMM 2: out(f32) = A(4096x1024)bf16 @ WT(1024x1024)bf16 + bias(f32).
// 64x128 tile (grid 512), BK=64 + chunk-XOR swizzle (r7 exact, FROZEN). --------
__global__ __launch_bounds__(256) void gemm_proj(const u16* __restrict__ A,
                                                 const u16* __restrict__ WT,
                                                 const float* __restrict__ bias,
                                                 float* __restrict__ out) {
  const int K = C_;
  __shared__ __align__(16) u16 As[2][64 * 64];   // 16 KB
  __shared__ __align__(16) u16 Bs[2][128 * 64];  // 32 KB
  int tid = threadIdx.x;
  int lane = tid & 63, wave = tid >> 6;
  int quad = lane >> 4, lr = lane & 15;
  int m0 = blockIdx.y * 64, n0 = blockIdx.x * 128;
  int wcol = wave * 32;
  int srow = lane >> 3;
  int schunk = (lane & 7) ^ srow;  // pre-swizzled global source chunk

  int koff0 = ((quad ^ (lr & 7)) << 3);
  int koff1 = (((4 | quad) ^ (lr & 7)) << 3);

  f32x4 zero = {0.f, 0.f, 0.f, 0.f};
  f32x4 acc[4][2];
#pragma unroll
  for (int i = 0; i < 4; i++)
#pragma unroll
    for (int j = 0; j < 2; j++) acc[i][j] = zero;

  const u16* ga = A + (size_t)(m0 + wave * 16 + srow) * K + schunk * 8;
  const u16* gb = WT + (size_t)(n0 + wave * 32 + srow) * K + schunk * 8;

  // prologue: A rows wave*16 + {0,8}; B rows wave*32 + {0,8,16,24}
  load_lds16(ga, &As[0][(wave * 16) * 64]);
  load_lds16(ga + (size_t)8 * K, &As[0][(wave * 16 + 8) * 64]);
#pragma unroll
  for (int l = 0; l < 4; l++)
    load_lds16(gb + (size_t)(l * 8) * K, &Bs[0][(wave * 32 + l * 8) * 64]);

  int buf = 0;
  for (int k0 = 0; k0 < K; k0 += 64) {
    __syncthreads();
    if (k0 + 64 < K) {
      load_lds16(ga + k0 + 64, &As[buf ^ 1][(wave * 16) * 64]);
      load_lds16(ga + (size_t)8 * K + k0 + 64, &As[buf ^ 1][(wave * 16 + 8) * 64]);
#pragma unroll
      for (int l = 0; l < 4; l++)
        load_lds16(gb + (size_t)(l * 8) * K + k0 + 64, &Bs[buf ^ 1][(wave * 32 + l * 8) * 64]);
    }
    bfrag8 af[4][2], bf[2][2];
#pragma unroll
    for (int i = 0; i < 4; i++) {
      const u16* ar = &As[buf][(i * 16 + lr) * 64];
      af[i][0] = *(const bfrag8*)(ar + koff0);
      af[i][1] = *(const bfrag8*)(ar + koff1);
    }
#pragma unroll
    for (int j = 0; j < 2; j++) {
      const u16* br = &Bs[buf][(wcol + j * 16 + lr) * 64];
      bf[j][0] = *(const bfrag8*)(br + koff0);
      bf[j][1] = *(const bfrag8*)(br + koff1);
    }
#pragma unroll
    for (int i = 0; i < 4; i++)
#pragma unroll
      for (int j = 0; j < 2; j++) {
        acc[i][j] = MFMA_BF16(af[i][0], bf[j][0], acc[i][j]);
        acc[i][j] = MFMA_BF16(af[i][1], bf[j][1], acc[i][j]);
      }
    buf ^= 1;
  }

#pragma unroll
  for (int i = 0; i < 4; i++)
#pragma unroll
    for (int r = 0; r < 4; r++) {
      int m = m0 + i * 16 + quad * 4 + r;
#pragma unroll
      for (int j = 0; j < 2; j++) {
        int n = n0 + wcol + j * 16 + lr;
        out[(size_t)m * C_ + n] = acc[i][j][r] + bias[n];
      }
    }
}

extern "C" void kernel_launch(void* const* d_in, const int* in_sizes, int n_in,
                              void* d_out, int out_size, void* d_ws, size_t ws_size,
                              hipStream_t stream) {
  const float* x = (const float*)d_in[0];       // [4096,1024] f32
  const float* w_qkv = (const float*)d_in[1];   // [1024,3072] f32
  const float* w_proj = (const float*)d_in[2];  // [1024,1024] f32
  const float* b_proj = (const float*)d_in[3];  // [1024] f32

  char* w = (char*)d_ws;
  u16* xb = (u16*)(w + 256);                 // 4096*1024 bf16 (A for gemm_qkv)
  u16* regA = xb + (size_t)4096 * 1024;      // max(wqkvT, abuf)
  u16* wqkvT = regA;                         // 3072*1024 (dead after gemm_qkv)
  u16* abuf = regA;                          // 4096*1024 (written by attn)
  u16* wprojT = regA + (size_t)4096 * 1024;  // 1024*1024
  u16* qbuf = wprojT + (size_t)1024 * 1024;
  u16* kbuf = qbuf + (size_t)B_ * H_ * T_ * D_;
  u16* vtb = kbuf + (size_t)B_ * H_ * T_ * D_;  // V^T [bh][d][t] (written by gemm_qkv)

  prep<<<3072, 256, 0, stream>>>(x, xb, w_qkv, wqkvT, w_proj, wprojT);
  gemm_qkv_rope<<<dim3(NQKV_ / 128, (B_ * T_) / 128), 256, 0, stream>>>(xb, wqkvT, qbuf, kbuf, vtb);
  attn_k<<<512, 512, 0, stream>>>(qbuf, kbuf, vtb, abuf);
  gemm_proj<<<dim3(C_ / 128, (B_ * T_) / 64), 256, 0, stream>>>(abuf, wprojT, b_proj, (float*)d_out);
}

// Round 9
// 192.024 us; speedup vs baseline: 1.0537x; 1.0537x over previous
//
#include <hip/hip_runtime.h>
#include <math.h>

typedef unsigned short u16;
typedef unsigned int u32;
typedef __bf16 bfrag8 __attribute__((ext_vector_type(8)));
typedef float f32x4 __attribute__((ext_vector_type(4)));

#define B_ 2
#define T_ 2048
#define H_ 16
#define D_ 64
#define C_ 1024
#define NQKV_ 3072

#define MFMA_BF16(a, b, c) __builtin_amdgcn_mfma_f32_16x16x32_bf16((a), (b), (c), 0, 0, 0)

__device__ __forceinline__ u16 f2bf(float f) {
  u32 u = __builtin_bit_cast(u32, f);
  u += 0x7fffu + ((u >> 16) & 1u);  // RNE
  return (u16)(u >> 16);
}

// async global->LDS, 16B/lane; lds dest = wave-uniform base + lane*16
__device__ __forceinline__ void load_lds16(const u16* gp, u16* lp) {
  __builtin_amdgcn_global_load_lds(
      (const __attribute__((address_space(1))) u32*)(const void*)gp,
      (__attribute__((address_space(3))) u32*)(void*)lp, 16, 0, 0);
}

// -------- fused prep: convert x (f32->bf16) + transpose both weights. --------
__global__ __launch_bounds__(256) void prep(const float* __restrict__ x,
                                            u16* __restrict__ xb,
                                            const float* __restrict__ wqkv,
                                            u16* __restrict__ wqkvT,
                                            const float* __restrict__ wproj,
                                            u16* __restrict__ wprojT) {
  int bid = blockIdx.x;
  int tid = threadIdx.x;
  __shared__ u16 tile[64][65];
  if (bid < 2048) {
    size_t i = ((size_t)bid * 256 + tid) * 8;
    const float* s = x + i;
    float4 a = *(const float4*)s, b = *(const float4*)(s + 4);
    union { uint4 v; u16 h[8]; } t;
    t.h[0] = f2bf(a.x); t.h[1] = f2bf(a.y); t.h[2] = f2bf(a.z); t.h[3] = f2bf(a.w);
    t.h[4] = f2bf(b.x); t.h[5] = f2bf(b.y); t.h[6] = f2bf(b.z); t.h[7] = f2bf(b.w);
    *(uint4*)(xb + i) = t.v;
    return;
  }
  const float* src;
  u16* dst;
  int N, bx, by;
  if (bid < 2816) {
    int rel = bid - 2048;
    src = wqkv; dst = wqkvT; N = NQKV_;
    bx = (rel % 48) * 64; by = (rel / 48) * 64;
  } else {
    int rel = bid - 2816;
    src = wproj; dst = wprojT; N = C_;
    bx = (rel & 15) * 64; by = (rel >> 4) * 64;
  }
  for (int idx = tid; idx < 4096; idx += 256) {
    int r = idx >> 6, c = idx & 63;
    tile[r][c] = f2bf(src[(size_t)(by + r) * N + bx + c]);
  }
  __syncthreads();
  for (int idx = tid; idx < 4096; idx += 256) {
    int r = idx >> 6, c = idx & 63;
    dst[(size_t)(bx + r) * C_ + by + c] = tile[c][r];
  }
}

// -------- GEMM 1: qkv = X(4096x1024)bf16 @ WT(3072x1024)bf16, RoPE epilogue.
// 128x128 tile, BK=64, dbuf chunk-XOR-swizzled LDS (r5-proven 45.5us, conflicts=0).
// REVERTED from r8's B-direct (62.5us: per-iter global B loads sat synchronously on
// the MFMA critical path - LDS staging is prefetched, L2 loads are not). FROZEN.
// q-scale now 0.125*log2e so attn can use exp2 directly (q feeds only attn). --------
__global__ __launch_bounds__(256) void gemm_qkv_rope(const u16* __restrict__ X,
                                                     const u16* __restrict__ WT,
                                                     u16* __restrict__ qb,
                                                     u16* __restrict__ kb,
                                                     u16* __restrict__ vtb) {
  const int K = C_;
  __shared__ __align__(16) u16 As[2][128 * 64];  // 32 KB
  __shared__ __align__(16) u16 Bs[2][128 * 64];  // 32 KB
  int tid = threadIdx.x;
  int lane = tid & 63, wave = tid >> 6;
  int quad = lane >> 4, lr = lane & 15;
  int m0 = blockIdx.y * 128, n0 = blockIdx.x * 128;
  int wrow = (wave >> 1) * 64, wcol = (wave & 1) * 64;
  int r0 = wave * 32;  // this wave's staging row base (32 rows per wave)
  int srow = lane >> 3;
  int schunk = (lane & 7) ^ srow;  // pre-swizzled global source chunk

  // read-side swizzled chunk offsets (u16 units): logical chunk (ks*4+quad) ^ (row&7)
  int koff0 = ((quad ^ (lr & 7)) << 3);
  int koff1 = (((4 | quad) ^ (lr & 7)) << 3);

  f32x4 zero = {0.f, 0.f, 0.f, 0.f};
  f32x4 acc[4][4];
#pragma unroll
  for (int i = 0; i < 4; i++)
#pragma unroll
    for (int j = 0; j < 4; j++) acc[i][j] = zero;

  const u16* ga = X + (size_t)(m0 + r0 + srow) * K + schunk * 8;
  const u16* gb = WT + (size_t)(n0 + r0 + srow) * K + schunk * 8;

  // prologue: stage tile 0 (8 loads/thread: 4 A-rowgroups + 4 B-rowgroups)
#pragma unroll
  for (int l = 0; l < 4; l++) {
    load_lds16(ga + (size_t)(l * 8) * K, &As[0][(r0 + l * 8) * 64]);
    load_lds16(gb + (size_t)(l * 8) * K, &Bs[0][(r0 + l * 8) * 64]);
  }

  int buf = 0;
  for (int k0 = 0; k0 < K; k0 += 64) {
    __syncthreads();  // drains tile-k0 loads (issued one compute phase ago)
    if (k0 + 64 < K) {
#pragma unroll
      for (int l = 0; l < 4; l++) {
        load_lds16(ga + (size_t)(l * 8) * K + k0 + 64, &As[buf ^ 1][(r0 + l * 8) * 64]);
        load_lds16(gb + (size_t)(l * 8) * K + k0 + 64, &Bs[buf ^ 1][(r0 + l * 8) * 64]);
      }
    }
    bfrag8 af[4][2], bf[4][2];
#pragma unroll
    for (int i = 0; i < 4; i++) {
      const u16* ar = &As[buf][(wrow + i * 16 + lr) * 64];
      af[i][0] = *(const bfrag8*)(ar + koff0);
      af[i][1] = *(const bfrag8*)(ar + koff1);
    }
#pragma unroll
    for (int j = 0; j < 4; j++) {
      const u16* br = &Bs[buf][(wcol + j * 16 + lr) * 64];
      bf[j][0] = *(const bfrag8*)(br + koff0);
      bf[j][1] = *(const bfrag8*)(br + koff1);
    }
#pragma unroll
    for (int i = 0; i < 4; i++)
#pragma unroll
      for (int j = 0; j < 4; j++) {
        acc[i][j] = MFMA_BF16(af[i][0], bf[j][0], acc[i][j]);
        acc[i][j] = MFMA_BF16(af[i][1], bf[j][1], acc[i][j]);
      }
    buf ^= 1;
  }

  int colbase = n0 + wcol;
  int which = colbase >> 10;  // 0=q 1=k 2=v
  int h = (colbase & 1023) >> 6;
  if (which < 2) {
    u16* dst = which == 0 ? qb : kb;
    // q pre-scaled by 1/8 * log2(e): attn computes P = exp2(S) directly
    float sc0 = (which == 0) ? 0.18033688011112042f : 1.0f;
    float fr0 = __expf(-0.28782313662425574f * (float)lr);        // ln(10000)/32
    float fr1 = __expf(-0.28782313662425574f * (float)(16 + lr));
#pragma unroll
    for (int i = 0; i < 4; i++) {
#pragma unroll
      for (int r = 0; r < 4; r++) {
        int m = m0 + wrow + i * 16 + quad * 4 + r;
        int b = m >> 11, tt = m & 2047;
        size_t base = ((size_t)(b * H_ + h) * T_ + tt) * D_;
        float sn, cs;
        __sincosf((float)tt * fr0, &sn, &cs);
        dst[base + lr] = f2bf((acc[i][0][r] * cs - acc[i][2][r] * sn) * sc0);
        dst[base + lr + 32] = f2bf((acc[i][0][r] * sn + acc[i][2][r] * cs) * sc0);
        __sincosf((float)tt * fr1, &sn, &cs);
        dst[base + 16 + lr] = f2bf((acc[i][1][r] * cs - acc[i][3][r] * sn) * sc0);
        dst[base + 48 + lr] = f2bf((acc[i][1][r] * sn + acc[i][3][r] * cs) * sc0);
      }
    }
  } else {
    // V: write transposed [bh][d][t]; lane holds 4 consecutive t per (i,j) -> 8B store
#pragma unroll
    for (int i = 0; i < 4; i++) {
      int mb = m0 + wrow + i * 16 + quad * 4;  // 4 consecutive t from here (same b)
      int b = mb >> 11, tt = mb & 2047;
      u16* vb = vtb + ((size_t)(b * H_ + h) * D_) * T_ + tt;
#pragma unroll
      for (int j = 0; j < 4; j++) {
        union { uint2 v; u16 hh[4]; } pk;
#pragma unroll
        for (int r = 0; r < 4; r++) pk.hh[r] = f2bf(acc[i][j][r]);
        *(uint2*)(vb + (size_t)(j * 16 + lr) * T_) = pk.v;
      }
    }
  }
}

// -------- attention: causal, S^T formulation, q-tile 128 (8 waves, 512 thr,
// 16 q-rows/wave), kv-tile 64, dbuf + single barrier/iter, heavy-first blocks,
// XOR-swizzled K/V LDS. NEW r9 (VALU cut on the serial softmax path):
//  * P = exp2(S) directly (log2e folded into q-scale upstream) — deletes 16 v_mul/iter
//  * bf16 pack via compiler cvt_pk (__bf16 casts) — deletes ~32 VALU/iter ----
__global__ __launch_bounds__(512) void attn_k(const u16* __restrict__ qb,
                                              const u16* __restrict__ kb,
                                              const u16* __restrict__ vtb,
                                              u16* __restrict__ ob) {
  __shared__ __align__(16) u16 Ks[2][64 * 64];   // [t][chunk^t&7]  8 KB each
  __shared__ __align__(16) u16 Vt[2][64 * 64];   // [d][chunk^d&7]
  __shared__ __align__(16) u16 Pst[8][16 * 72];  // per-wave P [q=16][t=64 +pad]
  int tid = threadIdx.x;
  int lane = tid & 63, wave = tid >> 6;
  int quad = lane >> 4, lr = lane & 15;
  int i = blockIdx.x;
  int bq = 15 - (i >> 5);  // heavy blocks dispatched first (16 q-blocks of 128)
  int bh = i & 31;
  int b = bh >> 4, h = bh & 15;
  const u16* Q = qb + (size_t)bh * T_ * D_;
  const u16* Kp = kb + (size_t)bh * T_ * D_;
  const u16* Vp = vtb + (size_t)bh * D_ * T_;
  int qr0 = bq * 128 + wave * 16;  // this wave's q-row base
  int r0v = wave * 8;              // staging row base (8 rows/wave)
  int sr = lane >> 3;
  int sc = (((lane & 7) ^ sr) * 8);  // XOR-swizzled staging column

  // read-side swizzled chunk offsets (u16 units), constant per lane
  int koff0 = ((quad ^ (lr & 7)) << 3);
  int koff1 = (((4 | quad) ^ (lr & 7)) << 3);

  // Q fragment as MFMA B-operand: B[n=q][k=d] (from global, unswizzled)
  bfrag8 qf[2];
#pragma unroll
  for (int ks = 0; ks < 2; ks++)
    qf[ks] = *(const bfrag8*)(Q + (size_t)(qr0 + lr) * D_ + ks * 32 + quad * 8);

  f32x4 zero = {0.f, 0.f, 0.f, 0.f};
  f32x4 o[4];
#pragma unroll
  for (int nn = 0; nn < 4; nn++) o[nn] = zero;
  float psum = 0.f;

  const u16* gk = Kp + (size_t)(r0v + sr) * D_ + sc;
  const u16* gv = Vp + (size_t)(r0v + sr) * T_ + sc;
  int niter = 2 * bq + 2;                // kv tiles covering bq*128+128 rows
  int wlast = 2 * bq + (wave >> 2);      // this wave's causal last tile
  int qloc = (wave & 3) * 16 + lr;       // q-pos within last tile

  load_lds16(gk, &Ks[0][r0v * 64]);
  load_lds16(gv, &Vt[0][r0v * 64]);

  int buf = 0;
  for (int it = 0; it < niter; it++) {
    __syncthreads();  // drains loads for tile `it` (issued one compute-phase ago)
    if (it + 1 < niter) {
      int tkn = (it + 1) * 64;
      load_lds16(gk + (size_t)tkn * D_, &Ks[buf ^ 1][r0v * 64]);
      load_lds16(gv + tkn, &Vt[buf ^ 1][r0v * 64]);
    }
    if (it <= wlast) {  // wave-uniform: waves past causal region idle (barriers kept)
      const u16* ks_ = Ks[buf];
      const u16* vt_ = Vt[buf];

      // S^T = K Q^T : 64 kv-rows x 16 q-cols (A=K-frag swizzled, B=Q-frag)
      f32x4 s[4];
#pragma unroll
      for (int j = 0; j < 4; j++) s[j] = zero;
#pragma unroll
      for (int j = 0; j < 4; j++) {
        bfrag8 kf0 = *(const bfrag8*)&ks_[(j * 16 + lr) * 64 + koff0];
        bfrag8 kf1 = *(const bfrag8*)&ks_[(j * 16 + lr) * 64 + koff1];
        s[j] = MFMA_BF16(kf0, qf[0], s[j]);
        s[j] = MFMA_BF16(kf1, qf[1], s[j]);
      }

      // P = exp2(S) (log2e pre-folded into q) + compiler cvt_pk bf16 pack
      bool edge = (it == wlast);  // wave-uniform
#pragma unroll
      for (int j = 0; j < 4; j++) {
        float p[4];
#pragma unroll
        for (int r = 0; r < 4; r++) {
          float e = exp2f(s[j][r]);
          if (edge) {
            int kvloc = j * 16 + quad * 4 + r;
            e = (kvloc <= qloc) ? e : 0.f;
          }
          p[r] = e;
          psum += e;
        }
        union { uint2 v; __bf16 h[4]; } pk;
        pk.h[0] = (__bf16)p[0];
        pk.h[1] = (__bf16)p[1];
        pk.h[2] = (__bf16)p[2];
        pk.h[3] = (__bf16)p[3];
        *(uint2*)&Pst[wave][lr * 72 + j * 16 + quad * 4] = pk.v;
      }

      // O += P V : A = P[q][t] (b128 from Pst), B = V^T[d][t] (swizzled)
#pragma unroll
      for (int ks = 0; ks < 2; ks++) {
        bfrag8 pf = *(const bfrag8*)&Pst[wave][lr * 72 + ks * 32 + quad * 8];
        int ko = ks ? koff1 : koff0;
#pragma unroll
        for (int nn = 0; nn < 4; nn++) {
          bfrag8 vf = *(const bfrag8*)&vt_[(nn * 16 + lr) * 64 + ko];
          o[nn] = MFMA_BF16(pf, vf, o[nn]);
        }
      }
    }
    buf ^= 1;
  }

  // total row-sum: reduce over the 4 quads
  float l = psum;
  l += __shfl_xor(l, 16, 64);
  l += __shfl_xor(l, 32, 64);
  float linv = 1.0f / l;

#pragma unroll
  for (int r = 0; r < 4; r++) {
    float lrec = __shfl(linv, quad * 4 + r, 64);
    int row = qr0 + quad * 4 + r;
#pragma unroll
    for (int nn = 0; nn < 4; nn++)
      ob[(size_t)(b * T_ + row) * C_ + h * 64 + nn * 16 + lr] = f2bf(o[nn][r] * lrec);
  }
}

// -------- GEMM 2: out(f32) = A(4096x1024)bf16 @ WT(1024x1024)bf16 + bias(f32).
// 64x128 tile (grid 512), BK=64 + chunk-XOR swizzle (r7 exact, FROZEN). --------
__global__ __launch_bounds__(256) void gemm_proj(const u16* __restrict__ A,
                                                 const u16* __restrict__ WT,
                                                 const float* __restrict__ bias,
                                                 float* __restrict__ out) {
  const int K = C_;
  __shared__ __align__(16) u16 As[2][64 * 64];   // 16 KB
  __shared__ __align__(16) u16 Bs[2][128 * 64];  // 32 KB
  int tid = threadIdx.x;
  int lane = tid & 63, wave = tid >> 6;
  int quad = lane >> 4, lr = lane & 15;
  int m0 = blockIdx.y * 64, n0 = blockIdx.x * 128;
  int wcol = wave * 32;
  int srow = lane >> 3;
  int schunk = (lane & 7) ^ srow;  // pre-swizzled global source chunk

  int koff0 = ((quad ^ (lr & 7)) << 3);
  int koff1 = (((4 | quad) ^ (lr & 7)) << 3);

  f32x4 zero = {0.f, 0.f, 0.f, 0.f};
  f32x4 acc[4][2];
#pragma unroll
  for (int i = 0; i < 4; i++)
#pragma unroll
    for (int j = 0; j < 2; j++) acc[i][j] = zero;

  const u16* ga = A + (size_t)(m0 + wave * 16 + srow) * K + schunk * 8;
  const u16* gb = WT + (size_t)(n0 + wave * 32 + srow) * K + schunk * 8;

  // prologue: A rows wave*16 + {0,8}; B rows wave*32 + {0,8,16,24}
  load_lds16(ga, &As[0][(wave * 16) * 64]);
  load_lds16(ga + (size_t)8 * K, &As[0][(wave * 16 + 8) * 64]);
#pragma unroll
  for (int l = 0; l < 4; l++)
    load_lds16(gb + (size_t)(l * 8) * K, &Bs[0][(wave * 32 + l * 8) * 64]);

  int buf = 0;
  for (int k0 = 0; k0 < K; k0 += 64) {
    __syncthreads();
    if (k0 + 64 < K) {
      load_lds16(ga + k0 + 64, &As[buf ^ 1][(wave * 16) * 64]);
      load_lds16(ga + (size_t)8 * K + k0 + 64, &As[buf ^ 1][(wave * 16 + 8) * 64]);
#pragma unroll
      for (int l = 0; l < 4; l++)
        load_lds16(gb + (size_t)(l * 8) * K + k0 + 64, &Bs[buf ^ 1][(wave * 32 + l * 8) * 64]);
    }
    bfrag8 af[4][2], bf[2][2];
#pragma unroll
    for (int i = 0; i < 4; i++) {
      const u16* ar = &As[buf][(i * 16 + lr) * 64];
      af[i][0] = *(const bfrag8*)(ar + koff0);
      af[i][1] = *(const bfrag8*)(ar + koff1);
    }
#pragma unroll
    for (int j = 0; j < 2; j++) {
      const u16* br = &Bs[buf][(wcol + j * 16 + lr) * 64];
      bf[j][0] = *(const bfrag8*)(br + koff0);
      bf[j][1] = *(const bfrag8*)(br + koff1);
    }
#pragma unroll
    for (int i = 0; i < 4; i++)
#pragma unroll
      for (int j = 0; j < 2; j++) {
        acc[i][j] = MFMA_BF16(af[i][0], bf[j][0], acc[i][j]);
        acc[i][j] = MFMA_BF16(af[i][1], bf[j][1], acc[i][j]);
      }
    buf ^= 1;
  }

#pragma unroll
  for (int i = 0; i < 4; i++)
#pragma unroll
    for (int r = 0; r < 4; r++) {
      int m = m0 + i * 16 + quad * 4 + r;
#pragma unroll
      for (int j = 0; j < 2; j++) {
        int n = n0 + wcol + j * 16 + lr;
        out[(size_t)m * C_ + n] = acc[i][j][r] + bias[n];
      }
    }
}

extern "C" void kernel_launch(void* const* d_in, const int* in_sizes, int n_in,
                              void* d_out, int out_size, void* d_ws, size_t ws_size,
                              hipStream_t stream) {
  const float* x = (const float*)d_in[0];       // [4096,1024] f32
  const float* w_qkv = (const float*)d_in[1];   // [1024,3072] f32
  const float* w_proj = (const float*)d_in[2];  // [1024,1024] f32
  const float* b_proj = (const float*)d_in[3];  // [1024] f32

  char* w = (char*)d_ws;
  u16* xb = (u16*)(w + 256);                 // 4096*1024 bf16 (A for gemm_qkv)
  u16* regA = xb + (size_t)4096 * 1024;      // max(wqkvT, abuf)
  u16* wqkvT = regA;                         // 3072*1024 (dead after gemm_qkv)
  u16* abuf = regA;                          // 4096*1024 (written by attn)
  u16* wprojT = regA + (size_t)4096 * 1024;  // 1024*1024
  u16* qbuf = wprojT + (size_t)1024 * 1024;
  u16* kbuf = qbuf + (size_t)B_ * H_ * T_ * D_;
  u16* vtb = kbuf + (size_t)B_ * H_ * T_ * D_;  // V^T [bh][d][t] (written by gemm_qkv)

  prep<<<3072, 256, 0, stream>>>(x, xb, w_qkv, wqkvT, w_proj, wprojT);
  gemm_qkv_rope<<<dim3(NQKV_ / 128, (B_ * T_) / 128), 256, 0, stream>>>(xb, wqkvT, qbuf, kbuf, vtb);
  attn_k<<<512, 512, 0, stream>>>(qbuf, kbuf, vtb, abuf);
  gemm_proj<<<dim3(C_ / 128, (B_ * T_) / 64), 256, 0, stream>>>(abuf, wprojT, b_proj, (float*)d_out);
}

// Round 11
// 187.210 us; speedup vs baseline: 1.0808x; 1.0257x over previous
//
#include <hip/hip_runtime.h>
#include <math.h>

typedef unsigned short u16;
typedef unsigned int u32;
typedef __bf16 bfrag8 __attribute__((ext_vector_type(8)));
typedef float f32x4 __attribute__((ext_vector_type(4)));

#define B_ 2
#define T_ 2048
#define H_ 16
#define D_ 64
#define C_ 1024
#define NQKV_ 3072

#define MFMA_BF16(a, b, c) __builtin_amdgcn_mfma_f32_16x16x32_bf16((a), (b), (c), 0, 0, 0)

__device__ __forceinline__ u16 f2bf(float f) {
  u32 u = __builtin_bit_cast(u32, f);
  u += 0x7fffu + ((u >> 16) & 1u);  // RNE
  return (u16)(u >> 16);
}

// exp2 via the target builtin: lowers to a single v_exp_f32 WITH the TRANS-op
// hazard wait-states the compiler owes dependent reads. (r10's raw inline-asm
// v_exp_f32 hid the instruction class -> missed wait-state -> absmax 0.56 FAIL.)
__device__ __forceinline__ float exp2_fast(float x) {
#if __has_builtin(__builtin_amdgcn_exp2f)
  return __builtin_amdgcn_exp2f(x);
#else
  return __expf(x * 0.6931471805599453f);
#endif
}

// async global->LDS, 16B/lane; lds dest = wave-uniform base + lane*16
__device__ __forceinline__ void load_lds16(const u16* gp, u16* lp) {
  __builtin_amdgcn_global_load_lds(
      (const __attribute__((address_space(1))) u32*)(const void*)gp,
      (__attribute__((address_space(3))) u32*)(void*)lp, 16, 0, 0);
}

// -------- fused prep: convert x (f32->bf16) + transpose both weights. --------
__global__ __launch_bounds__(256) void prep(const float* __restrict__ x,
                                            u16* __restrict__ xb,
                                            const float* __restrict__ wqkv,
                                            u16* __restrict__ wqkvT,
                                            const float* __restrict__ wproj,
                                            u16* __restrict__ wprojT) {
  int bid = blockIdx.x;
  int tid = threadIdx.x;
  __shared__ u16 tile[64][65];
  if (bid < 2048) {
    size_t i = ((size_t)bid * 256 + tid) * 8;
    const float* s = x + i;
    float4 a = *(const float4*)s, b = *(const float4*)(s + 4);
    union { uint4 v; u16 h[8]; } t;
    t.h[0] = f2bf(a.x); t.h[1] = f2bf(a.y); t.h[2] = f2bf(a.z); t.h[3] = f2bf(a.w);
    t.h[4] = f2bf(b.x); t.h[5] = f2bf(b.y); t.h[6] = f2bf(b.z); t.h[7] = f2bf(b.w);
    *(uint4*)(xb + i) = t.v;
    return;
  }
  const float* src;
  u16* dst;
  int N, bx, by;
  if (bid < 2816) {
    int rel = bid - 2048;
    src = wqkv; dst = wqkvT; N = NQKV_;
    bx = (rel % 48) * 64; by = (rel / 48) * 64;
  } else {
    int rel = bid - 2816;
    src = wproj; dst = wprojT; N = C_;
    bx = (rel & 15) * 64; by = (rel >> 4) * 64;
  }
  for (int idx = tid; idx < 4096; idx += 256) {
    int r = idx >> 6, c = idx & 63;
    tile[r][c] = f2bf(src[(size_t)(by + r) * N + bx + c]);
  }
  __syncthreads();
  for (int idx = tid; idx < 4096; idx += 256) {
    int r = idx >> 6, c = idx & 63;
    dst[(size_t)(bx + r) * C_ + by + c] = tile[c][r];
  }
}

// -------- GEMM 1: qkv = X(4096x1024)bf16 @ WT(3072x1024)bf16, RoPE epilogue.
// 128x128 tile, BK=64, dbuf chunk-XOR-swizzled LDS (r5-proven, conflicts=0). FROZEN.
// q pre-scaled by 0.125*log2e: attn computes P = exp2(S) directly. --------
__global__ __launch_bounds__(256) void gemm_qkv_rope(const u16* __restrict__ X,
                                                     const u16* __restrict__ WT,
                                                     u16* __restrict__ qb,
                                                     u16* __restrict__ kb,
                                                     u16* __restrict__ vtb) {
  const int K = C_;
  __shared__ __align__(16) u16 As[2][128 * 64];  // 32 KB
  __shared__ __align__(16) u16 Bs[2][128 * 64];  // 32 KB
  int tid = threadIdx.x;
  int lane = tid & 63, wave = tid >> 6;
  int quad = lane >> 4, lr = lane & 15;
  int m0 = blockIdx.y * 128, n0 = blockIdx.x * 128;
  int wrow = (wave >> 1) * 64, wcol = (wave & 1) * 64;
  int r0 = wave * 32;  // this wave's staging row base (32 rows per wave)
  int srow = lane >> 3;
  int schunk = (lane & 7) ^ srow;  // pre-swizzled global source chunk

  // read-side swizzled chunk offsets (u16 units): logical chunk (ks*4+quad) ^ (row&7)
  int koff0 = ((quad ^ (lr & 7)) << 3);
  int koff1 = (((4 | quad) ^ (lr & 7)) << 3);

  f32x4 zero = {0.f, 0.f, 0.f, 0.f};
  f32x4 acc[4][4];
#pragma unroll
  for (int i = 0; i < 4; i++)
#pragma unroll
    for (int j = 0; j < 4; j++) acc[i][j] = zero;

  const u16* ga = X + (size_t)(m0 + r0 + srow) * K + schunk * 8;
  const u16* gb = WT + (size_t)(n0 + r0 + srow) * K + schunk * 8;

  // prologue: stage tile 0 (8 loads/thread: 4 A-rowgroups + 4 B-rowgroups)
#pragma unroll
  for (int l = 0; l < 4; l++) {
    load_lds16(ga + (size_t)(l * 8) * K, &As[0][(r0 + l * 8) * 64]);
    load_lds16(gb + (size_t)(l * 8) * K, &Bs[0][(r0 + l * 8) * 64]);
  }

  int buf = 0;
  for (int k0 = 0; k0 < K; k0 += 64) {
    __syncthreads();  // drains tile-k0 loads (issued one compute phase ago)
    if (k0 + 64 < K) {
#pragma unroll
      for (int l = 0; l < 4; l++) {
        load_lds16(ga + (size_t)(l * 8) * K + k0 + 64, &As[buf ^ 1][(r0 + l * 8) * 64]);
        load_lds16(gb + (size_t)(l * 8) * K + k0 + 64, &Bs[buf ^ 1][(r0 + l * 8) * 64]);
      }
    }
    bfrag8 af[4][2], bf[4][2];
#pragma unroll
    for (int i = 0; i < 4; i++) {
      const u16* ar = &As[buf][(wrow + i * 16 + lr) * 64];
      af[i][0] = *(const bfrag8*)(ar + koff0);
      af[i][1] = *(const bfrag8*)(ar + koff1);
    }
#pragma unroll
    for (int j = 0; j < 4; j++) {
      const u16* br = &Bs[buf][(wcol + j * 16 + lr) * 64];
      bf[j][0] = *(const bfrag8*)(br + koff0);
      bf[j][1] = *(const bfrag8*)(br + koff1);
    }
#pragma unroll
    for (int i = 0; i < 4; i++)
#pragma unroll
      for (int j = 0; j < 4; j++) {
        acc[i][j] = MFMA_BF16(af[i][0], bf[j][0], acc[i][j]);
        acc[i][j] = MFMA_BF16(af[i][1], bf[j][1], acc[i][j]);
      }
    buf ^= 1;
  }

  int colbase = n0 + wcol;
  int which = colbase >> 10;  // 0=q 1=k 2=v
  int h = (colbase & 1023) >> 6;
  if (which < 2) {
    u16* dst = which == 0 ? qb : kb;
    // q pre-scaled by 1/8 * log2(e): attn computes P = exp2(S) directly
    float sc0 = (which == 0) ? 0.18033688011112042f : 1.0f;
    float fr0 = __expf(-0.28782313662425574f * (float)lr);        // ln(10000)/32
    float fr1 = __expf(-0.28782313662425574f * (float)(16 + lr));
#pragma unroll
    for (int i = 0; i < 4; i++) {
#pragma unroll
      for (int r = 0; r < 4; r++) {
        int m = m0 + wrow + i * 16 + quad * 4 + r;
        int b = m >> 11, tt = m & 2047;
        size_t base = ((size_t)(b * H_ + h) * T_ + tt) * D_;
        float sn, cs;
        __sincosf((float)tt * fr0, &sn, &cs);
        dst[base + lr] = f2bf((acc[i][0][r] * cs - acc[i][2][r] * sn) * sc0);
        dst[base + lr + 32] = f2bf((acc[i][0][r] * sn + acc[i][2][r] * cs) * sc0);
        __sincosf((float)tt * fr1, &sn, &cs);
        dst[base + 16 + lr] = f2bf((acc[i][1][r] * cs - acc[i][3][r] * sn) * sc0);
        dst[base + 48 + lr] = f2bf((acc[i][1][r] * sn + acc[i][3][r] * cs) * sc0);
      }
    }
  } else {
    // V: write transposed [bh][d][t]; lane holds 4 consecutive t per (i,j) -> 8B store
#pragma unroll
    for (int i = 0; i < 4; i++) {
      int mb = m0 + wrow + i * 16 + quad * 4;  // 4 consecutive t from here (same b)
      int b = mb >> 11, tt = mb & 2047;
      u16* vb = vtb + ((size_t)(b * H_ + h) * D_) * T_ + tt;
#pragma unroll
      for (int j = 0; j < 4; j++) {
        union { uint2 v; u16 hh[4]; } pk;
#pragma unroll
        for (int r = 0; r < 4; r++) pk.hh[r] = f2bf(acc[i][j][r]);
        *(uint2*)(vb + (size_t)(j * 16 + lr) * T_) = pk.v;
      }
    }
  }
}

// -------- attention: causal, S^T formulation, q-tile 128 (8 waves, 512 thr,
// 16 q-rows/wave), kv-tile 64, dbuf + single barrier/iter, heavy-first blocks,
// XOR-swizzled K/V LDS. r11: r7-proven body + (a) exp2 via __builtin_amdgcn_exp2f
// (log2e folded into q upstream; single v_exp_f32, hazard handled by compiler),
// (b) r7 manual bf16 pair-pack, (c) 4-way psum accumulators. ----
__global__ __launch_bounds__(512) void attn_k(const u16* __restrict__ qb,
                                              const u16* __restrict__ kb,
                                              const u16* __restrict__ vtb,
                                              u16* __restrict__ ob) {
  __shared__ __align__(16) u16 Ks[2][64 * 64];   // [t][chunk^t&7]  8 KB each
  __shared__ __align__(16) u16 Vt[2][64 * 64];   // [d][chunk^d&7]
  __shared__ __align__(16) u16 Pst[8][16 * 72];  // per-wave P [q=16][t=64 +pad]
  int tid = threadIdx.x;
  int lane = tid & 63, wave = tid >> 6;
  int quad = lane >> 4, lr = lane & 15;
  int i = blockIdx.x;
  int bq = 15 - (i >> 5);  // heavy blocks dispatched first (16 q-blocks of 128)
  int bh = i & 31;
  int b = bh >> 4, h = bh & 15;
  const u16* Q = qb + (size_t)bh * T_ * D_;
  const u16* Kp = kb + (size_t)bh * T_ * D_;
  const u16* Vp = vtb + (size_t)bh * D_ * T_;
  int qr0 = bq * 128 + wave * 16;  // this wave's q-row base
  int r0v = wave * 8;              // staging row base (8 rows/wave)
  int sr = lane >> 3;
  int sc = (((lane & 7) ^ sr) * 8);  // XOR-swizzled staging column

  // read-side swizzled chunk offsets (u16 units), constant per lane
  int koff0 = ((quad ^ (lr & 7)) << 3);
  int koff1 = (((4 | quad) ^ (lr & 7)) << 3);

  // Q fragment as MFMA B-operand: B[n=q][k=d] (from global, unswizzled)
  bfrag8 qf[2];
#pragma unroll
  for (int ks = 0; ks < 2; ks++)
    qf[ks] = *(const bfrag8*)(Q + (size_t)(qr0 + lr) * D_ + ks * 32 + quad * 8);

  f32x4 zero = {0.f, 0.f, 0.f, 0.f};
  f32x4 o[4];
#pragma unroll
  for (int nn = 0; nn < 4; nn++) o[nn] = zero;
  float ps0 = 0.f, ps1 = 0.f, ps2 = 0.f, ps3 = 0.f;

  const u16* gk = Kp + (size_t)(r0v + sr) * D_ + sc;
  const u16* gv = Vp + (size_t)(r0v + sr) * T_ + sc;
  int niter = 2 * bq + 2;                // kv tiles covering bq*128+128 rows
  int wlast = 2 * bq + (wave >> 2);      // this wave's causal last tile
  int qloc = (wave & 3) * 16 + lr;       // q-pos within last tile

  load_lds16(gk, &Ks[0][r0v * 64]);
  load_lds16(gv, &Vt[0][r0v * 64]);

  int buf = 0;
  for (int it = 0; it < niter; it++) {
    __syncthreads();  // drains loads for tile `it` (issued one compute-phase ago)
    if (it + 1 < niter) {
      int tkn = (it + 1) * 64;
      load_lds16(gk + (size_t)tkn * D_, &Ks[buf ^ 1][r0v * 64]);
      load_lds16(gv + tkn, &Vt[buf ^ 1][r0v * 64]);
    }
    if (it <= wlast) {  // wave-uniform: waves past causal region idle (barriers kept)
      const u16* ks_ = Ks[buf];
      const u16* vt_ = Vt[buf];

      // S^T = K Q^T : 64 kv-rows x 16 q-cols (A=K-frag swizzled, B=Q-frag)
      f32x4 s[4];
#pragma unroll
      for (int j = 0; j < 4; j++) s[j] = zero;
#pragma unroll
      for (int j = 0; j < 4; j++) {
        bfrag8 kf0 = *(const bfrag8*)&ks_[(j * 16 + lr) * 64 + koff0];
        bfrag8 kf1 = *(const bfrag8*)&ks_[(j * 16 + lr) * 64 + koff1];
        s[j] = MFMA_BF16(kf0, qf[0], s[j]);
        s[j] = MFMA_BF16(kf1, qf[1], s[j]);
      }

      // P = exp2(S) (builtin v_exp_f32) + manual pair-pack + 4-way psum
      bool edge = (it == wlast);  // wave-uniform
#pragma unroll
      for (int j = 0; j < 4; j++) {
        float p[4];
#pragma unroll
        for (int r = 0; r < 4; r++) {
          float e = exp2_fast(s[j][r]);
          if (edge) {
            int kvloc = j * 16 + quad * 4 + r;
            e = (kvloc <= qloc) ? e : 0.f;
          }
          p[r] = e;
        }
        ps0 += p[0];
        ps1 += p[1];
        ps2 += p[2];
        ps3 += p[3];
        u32 u0 = __builtin_bit_cast(u32, p[0]) + 0x8000u;
        u32 u1 = __builtin_bit_cast(u32, p[1]) + 0x8000u;
        u32 u2 = __builtin_bit_cast(u32, p[2]) + 0x8000u;
        u32 u3 = __builtin_bit_cast(u32, p[3]) + 0x8000u;
        uint2 pk;
        pk.x = (u0 >> 16) | (u1 & 0xffff0000u);
        pk.y = (u2 >> 16) | (u3 & 0xffff0000u);
        *(uint2*)&Pst[wave][lr * 72 + j * 16 + quad * 4] = pk;
      }

      // O += P V : A = P[q][t] (b128 from Pst), B = V^T[d][t] (swizzled)
#pragma unroll
      for (int ks = 0; ks < 2; ks++) {
        bfrag8 pf = *(const bfrag8*)&Pst[wave][lr * 72 + ks * 32 + quad * 8];
        int ko = ks ? koff1 : koff0;
#pragma unroll
        for (int nn = 0; nn < 4; nn++) {
          bfrag8 vf = *(const bfrag8*)&vt_[(nn * 16 + lr) * 64 + ko];
          o[nn] = MFMA_BF16(pf, vf, o[nn]);
        }
      }
    }
    buf ^= 1;
  }

  // total row-sum: reduce over the 4 quads
  float l = (ps0 + ps1) + (ps2 + ps3);
  l += __shfl_xor(l, 16, 64);
  l += __shfl_xor(l, 32, 64);
  float linv = 1.0f / l;

#pragma unroll
  for (int r = 0; r < 4; r++) {
    float lrec = __shfl(linv, quad * 4 + r, 64);
    int row = qr0 + quad * 4 + r;
#pragma unroll
    for (int nn = 0; nn < 4; nn++)
      ob[(size_t)(b * T_ + row) * C_ + h * 64 + nn * 16 + lr] = f2bf(o[nn][r] * lrec);
  }
}

// -------- GEMM 2: out(f32) = A(4096x1024)bf16 @ WT(1024x1024)bf16 + bias(f32).
// 64x128 tile (grid 512), BK=64 + chunk-XOR swizzle (r7 exact, FROZEN). --------
__global__ __launch_bounds__(256) void gemm_proj(const u16* __restrict__ A,
                                                 const u16* __restrict__ WT,
                                                 const float* __restrict__ bias,
                                                 float* __restrict__ out) {
  const int K = C_;
  __shared__ __align__(16) u16 As[2][64 * 64];   // 16 KB
  __shared__ __align__(16) u16 Bs[2][128 * 64];  // 32 KB
  int tid = threadIdx.x;
  int lane = tid & 63, wave = tid >> 6;
  int quad = lane >> 4, lr = lane & 15;
  int m0 = blockIdx.y * 64, n0 = blockIdx.x * 128;
  int wcol = wave * 32;
  int srow = lane >> 3;
  int schunk = (lane & 7) ^ srow;  // pre-swizzled global source chunk

  int koff0 = ((quad ^ (lr & 7)) << 3);
  int koff1 = (((4 | quad) ^ (lr & 7)) << 3);

  f32x4 zero = {0.f, 0.f, 0.f, 0.f};
  f32x4 acc[4][2];
#pragma unroll
  for (int i = 0; i < 4; i++)
#pragma unroll
    for (int j = 0; j < 2; j++) acc[i][j] = zero;

  const u16* ga = A + (size_t)(m0 + wave * 16 + srow) * K + schunk * 8;
  const u16* gb = WT + (size_t)(n0 + wave * 32 + srow) * K + schunk * 8;

  // prologue: A rows wave*16 + {0,8}; B rows wave*32 + {0,8,16,24}
  load_lds16(ga, &As[0][(wave * 16) * 64]);
  load_lds16(ga + (size_t)8 * K, &As[0][(wave * 16 + 8) * 64]);
#pragma unroll
  for (int l = 0; l < 4; l++)
    load_lds16(gb + (size_t)(l * 8) * K, &Bs[0][(wave * 32 + l * 8) * 64]);

  int buf = 0;
  for (int k0 = 0; k0 < K; k0 += 64) {
    __syncthreads();
    if (k0 + 64 < K) {
      load_lds16(ga + k0 + 64, &As[buf ^ 1][(wave * 16) * 64]);
      load_lds16(ga + (size_t)8 * K + k0 + 64, &As[buf ^ 1][(wave * 16 + 8) * 64]);
#pragma unroll
      for (int l = 0; l < 4; l++)
        load_lds16(gb + (size_t)(l * 8) * K + k0 + 64, &Bs[buf ^ 1][(wave * 32 + l * 8) * 64]);
    }
    bfrag8 af[4][2], bf[2][2];
#pragma unroll
    for (int i = 0; i < 4; i++) {
      const u16* ar = &As[buf][(i * 16 + lr) * 64];
      af[i][0] = *(const bfrag8*)(ar + koff0);
      af[i][1] = *(const bfrag8*)(ar + koff1);
    }
#pragma unroll
    for (int j = 0; j < 2; j++) {
      const u16* br = &Bs[buf][(wcol + j * 16 + lr) * 64];
      bf[j][0] = *(const bfrag8*)(br + koff0);
      bf[j][1] = *(const bfrag8*)(br + koff1);
    }
#pragma unroll
    for (int i = 0; i < 4; i++)
#pragma unroll
      for (int j = 0; j < 2; j++) {
        acc[i][j] = MFMA_BF16(af[i][0], bf[j][0], acc[i][j]);
        acc[i][j] = MFMA_BF16(af[i][1], bf[j][1], acc[i][j]);
      }
    buf ^= 1;
  }

#pragma unroll
  for (int i = 0; i < 4; i++)
#pragma unroll
    for (int r = 0; r < 4; r++) {
      int m = m0 + i * 16 + quad * 4 + r;
#pragma unroll
      for (int j = 0; j < 2; j++) {
        int n = n0 + wcol + j * 16 + lr;
        out[(size_t)m * C_ + n] = acc[i][j][r] + bias[n];
      }
    }
}

extern "C" void kernel_launch(void* const* d_in, const int* in_sizes, int n_in,
                              void* d_out, int out_size, void* d_ws, size_t ws_size,
                              hipStream_t stream) {
  const float* x = (const float*)d_in[0];       // [4096,1024] f32
  const float* w_qkv = (const float*)d_in[1];   // [1024,3072] f32
  const float* w_proj = (const float*)d_in[2];  // [1024,1024] f32
  const float* b_proj = (const float*)d_in[3];  // [1024] f32

  char* w = (char*)d_ws;
  u16* xb = (u16*)(w + 256);                 // 4096*1024 bf16 (A for gemm_qkv)
  u16* regA = xb + (size_t)4096 * 1024;      // max(wqkvT, abuf)
  u16* wqkvT = regA;                         // 3072*1024 (dead after gemm_qkv)
  u16* abuf = regA;                          // 4096*1024 (written by attn)
  u16* wprojT = regA + (size_t)4096 * 1024;  // 1024*1024
  u16* qbuf = wprojT + (size_t)1024 * 1024;
  u16* kbuf = qbuf + (size_t)B_ * H_ * T_ * D_;
  u16* vtb = kbuf + (size_t)B_ * H_ * T_ * D_;  // V^T [bh][d][t] (written by gemm_qkv)

  prep<<<3072, 256, 0, stream>>>(x, xb, w_qkv, wqkvT, w_proj, wprojT);
  gemm_qkv_rope<<<dim3(NQKV_ / 128, (B_ * T_) / 128), 256, 0, stream>>>(xb, wqkvT, qbuf, kbuf, vtb);
  attn_k<<<512, 512, 0, stream>>>(qbuf, kbuf, vtb, abuf);
  gemm_proj<<<dim3(C_ / 128, (B_ * T_) / 64), 256, 0, stream>>>(abuf, wprojT, b_proj, (float*)d_out);
}

// Round 12
// 180.347 us; speedup vs baseline: 1.1219x; 1.0381x over previous
//
#include <hip/hip_runtime.h>
#include <math.h>

typedef unsigned short u16;
typedef unsigned int u32;
typedef __bf16 bfrag8 __attribute__((ext_vector_type(8)));
typedef float f32x4 __attribute__((ext_vector_type(4)));

#define B_ 2
#define T_ 2048
#define H_ 16
#define D_ 64
#define C_ 1024
#define NQKV_ 3072

#define MFMA_BF16(a, b, c) __builtin_amdgcn_mfma_f32_16x16x32_bf16((a), (b), (c), 0, 0, 0)

__device__ __forceinline__ u16 f2bf(float f) {
  u32 u = __builtin_bit_cast(u32, f);
  u += 0x7fffu + ((u >> 16) & 1u);  // RNE
  return (u16)(u >> 16);
}

// exp2 via the target builtin: single v_exp_f32 with compiler-managed TRANS hazard
__device__ __forceinline__ float exp2_fast(float x) {
#if __has_builtin(__builtin_amdgcn_exp2f)
  return __builtin_amdgcn_exp2f(x);
#else
  return __expf(x * 0.6931471805599453f);
#endif
}

// async global->LDS, 16B/lane; lds dest = wave-uniform base + lane*16
__device__ __forceinline__ void load_lds16(const u16* gp, u16* lp) {
  __builtin_amdgcn_global_load_lds(
      (const __attribute__((address_space(1))) u32*)(const void*)gp,
      (__attribute__((address_space(3))) u32*)(void*)lp, 16, 0, 0);
}

// -------- fused prep: convert x (f32->bf16) + transpose both weights. --------
__global__ __launch_bounds__(256) void prep(const float* __restrict__ x,
                                            u16* __restrict__ xb,
                                            const float* __restrict__ wqkv,
                                            u16* __restrict__ wqkvT,
                                            const float* __restrict__ wproj,
                                            u16* __restrict__ wprojT) {
  int bid = blockIdx.x;
  int tid = threadIdx.x;
  __shared__ u16 tile[64][65];
  if (bid < 2048) {
    size_t i = ((size_t)bid * 256 + tid) * 8;
    const float* s = x + i;
    float4 a = *(const float4*)s, b = *(const float4*)(s + 4);
    union { uint4 v; u16 h[8]; } t;
    t.h[0] = f2bf(a.x); t.h[1] = f2bf(a.y); t.h[2] = f2bf(a.z); t.h[3] = f2bf(a.w);
    t.h[4] = f2bf(b.x); t.h[5] = f2bf(b.y); t.h[6] = f2bf(b.z); t.h[7] = f2bf(b.w);
    *(uint4*)(xb + i) = t.v;
    return;
  }
  const float* src;
  u16* dst;
  int N, bx, by;
  if (bid < 2816) {
    int rel = bid - 2048;
    src = wqkv; dst = wqkvT; N = NQKV_;
    bx = (rel % 48) * 64; by = (rel / 48) * 64;
  } else {
    int rel = bid - 2816;
    src = wproj; dst = wprojT; N = C_;
    bx = (rel & 15) * 64; by = (rel >> 4) * 64;
  }
  for (int idx = tid; idx < 4096; idx += 256) {
    int r = idx >> 6, c = idx & 63;
    tile[r][c] = f2bf(src[(size_t)(by + r) * N + bx + c]);
  }
  __syncthreads();
  for (int idx = tid; idx < 4096; idx += 256) {
    int r = idx >> 6, c = idx & 63;
    dst[(size_t)(bx + r) * C_ + by + c] = tile[c][r];
  }
}

// -------- GEMM 1: qkv = X(4096x1024)bf16 @ WT(3072x1024)bf16, RoPE epilogue.
// 128x128 tile, BK=64, dbuf chunk-XOR-swizzled LDS (r5-proven, conflicts=0). FROZEN.
// q pre-scaled by 0.125*log2e: attn computes P = exp2(S) directly. --------
__global__ __launch_bounds__(256) void gemm_qkv_rope(const u16* __restrict__ X,
                                                     const u16* __restrict__ WT,
                                                     u16* __restrict__ qb,
                                                     u16* __restrict__ kb,
                                                     u16* __restrict__ vtb) {
  const int K = C_;
  __shared__ __align__(16) u16 As[2][128 * 64];  // 32 KB
  __shared__ __align__(16) u16 Bs[2][128 * 64];  // 32 KB
  int tid = threadIdx.x;
  int lane = tid & 63, wave = tid >> 6;
  int quad = lane >> 4, lr = lane & 15;
  int m0 = blockIdx.y * 128, n0 = blockIdx.x * 128;
  int wrow = (wave >> 1) * 64, wcol = (wave & 1) * 64;
  int r0 = wave * 32;  // this wave's staging row base (32 rows per wave)
  int srow = lane >> 3;
  int schunk = (lane & 7) ^ srow;  // pre-swizzled global source chunk

  // read-side swizzled chunk offsets (u16 units): logical chunk (ks*4+quad) ^ (row&7)
  int koff0 = ((quad ^ (lr & 7)) << 3);
  int koff1 = (((4 | quad) ^ (lr & 7)) << 3);

  f32x4 zero = {0.f, 0.f, 0.f, 0.f};
  f32x4 acc[4][4];
#pragma unroll
  for (int i = 0; i < 4; i++)
#pragma unroll
    for (int j = 0; j < 4; j++) acc[i][j] = zero;

  const u16* ga = X + (size_t)(m0 + r0 + srow) * K + schunk * 8;
  const u16* gb = WT + (size_t)(n0 + r0 + srow) * K + schunk * 8;

  // prologue: stage tile 0 (8 loads/thread: 4 A-rowgroups + 4 B-rowgroups)
#pragma unroll
  for (int l = 0; l < 4; l++) {
    load_lds16(ga + (size_t)(l * 8) * K, &As[0][(r0 + l * 8) * 64]);
    load_lds16(gb + (size_t)(l * 8) * K, &Bs[0][(r0 + l * 8) * 64]);
  }

  int buf = 0;
  for (int k0 = 0; k0 < K; k0 += 64) {
    __syncthreads();  // drains tile-k0 loads (issued one compute phase ago)
    if (k0 + 64 < K) {
#pragma unroll
      for (int l = 0; l < 4; l++) {
        load_lds16(ga + (size_t)(l * 8) * K + k0 + 64, &As[buf ^ 1][(r0 + l * 8) * 64]);
        load_lds16(gb + (size_t)(l * 8) * K + k0 + 64, &Bs[buf ^ 1][(r0 + l * 8) * 64]);
      }
    }
    bfrag8 af[4][2], bf[4][2];
#pragma unroll
    for (int i = 0; i < 4; i++) {
      const u16* ar = &As[buf][(wrow + i * 16 + lr) * 64];
      af[i][0] = *(const bfrag8*)(ar + koff0);
      af[i][1] = *(const bfrag8*)(ar + koff1);
    }
#pragma unroll
    for (int j = 0; j < 4; j++) {
      const u16* br = &Bs[buf][(wcol + j * 16 + lr) * 64];
      bf[j][0] = *(const bfrag8*)(br + koff0);
      bf[j][1] = *(const bfrag8*)(br + koff1);
    }
#pragma unroll
    for (int i = 0; i < 4; i++)
#pragma unroll
      for (int j = 0; j < 4; j++) {
        acc[i][j] = MFMA_BF16(af[i][0], bf[j][0], acc[i][j]);
        acc[i][j] = MFMA_BF16(af[i][1], bf[j][1], acc[i][j]);
      }
    buf ^= 1;
  }

  int colbase = n0 + wcol;
  int which = colbase >> 10;  // 0=q 1=k 2=v
  int h = (colbase & 1023) >> 6;
  if (which < 2) {
    u16* dst = which == 0 ? qb : kb;
    // q pre-scaled by 1/8 * log2(e): attn computes P = exp2(S) directly
    float sc0 = (which == 0) ? 0.18033688011112042f : 1.0f;
    float fr0 = __expf(-0.28782313662425574f * (float)lr);        // ln(10000)/32
    float fr1 = __expf(-0.28782313662425574f * (float)(16 + lr));
#pragma unroll
    for (int i = 0; i < 4; i++) {
#pragma unroll
      for (int r = 0; r < 4; r++) {
        int m = m0 + wrow + i * 16 + quad * 4 + r;
        int b = m >> 11, tt = m & 2047;
        size_t base = ((size_t)(b * H_ + h) * T_ + tt) * D_;
        float sn, cs;
        __sincosf((float)tt * fr0, &sn, &cs);
        dst[base + lr] = f2bf((acc[i][0][r] * cs - acc[i][2][r] * sn) * sc0);
        dst[base + lr + 32] = f2bf((acc[i][0][r] * sn + acc[i][2][r] * cs) * sc0);
        __sincosf((float)tt * fr1, &sn, &cs);
        dst[base + 16 + lr] = f2bf((acc[i][1][r] * cs - acc[i][3][r] * sn) * sc0);
        dst[base + 48 + lr] = f2bf((acc[i][1][r] * sn + acc[i][3][r] * cs) * sc0);
      }
    }
  } else {
    // V: write transposed [bh][d][t]; lane holds 4 consecutive t per (i,j) -> 8B store
#pragma unroll
    for (int i = 0; i < 4; i++) {
      int mb = m0 + wrow + i * 16 + quad * 4;  // 4 consecutive t from here (same b)
      int b = mb >> 11, tt = mb & 2047;
      u16* vb = vtb + ((size_t)(b * H_ + h) * D_) * T_ + tt;
#pragma unroll
      for (int j = 0; j < 4; j++) {
        union { uint2 v; u16 hh[4]; } pk;
#pragma unroll
        for (int r = 0; r < 4; r++) pk.hh[r] = f2bf(acc[i][j][r]);
        *(uint2*)(vb + (size_t)(j * 16 + lr) * T_) = pk.v;
      }
    }
  }
}

// -------- attention: causal, S^T formulation, q-tile 128 (8 waves, 512 thr,
// 16 q-rows/wave). r12: kv STAGING TILE 128 (2 compute subtiles of 64 per barrier)
// -> barriers/vmcnt-drains on the critical heavy block halve (32->16) and each
// staging interval has 2x compute to cover load latency (r5 mechanism transferred).
// Pst re-strided 72->64 with 16B-chunk XOR swizzle (conflict-free, saves LDS)
// -> total LDS exactly 80KB = 2 blocks/CU. ----
__global__ __launch_bounds__(512) void attn_k(const u16* __restrict__ qb,
                                              const u16* __restrict__ kb,
                                              const u16* __restrict__ vtb,
                                              u16* __restrict__ ob) {
  __shared__ __align__(16) u16 Ks[2][128 * 64];  // [t][chunk^(t&7)]   16 KB each
  __shared__ __align__(16) u16 Vt[2][64 * 128];  // [d][chunk16^(d&7)] 16 KB each
  __shared__ __align__(16) u16 Pst[8][16 * 64];  // per-wave P, chunk16-XOR swizzled
  int tid = threadIdx.x;
  int lane = tid & 63, wave = tid >> 6;
  int quad = lane >> 4, lr = lane & 15;
  int i = blockIdx.x;
  int bq = 15 - (i >> 5);  // heavy blocks dispatched first (16 q-blocks of 128)
  int bh = i & 31;
  int b = bh >> 4, h2 = bh & 15;
  const u16* Q = qb + (size_t)bh * T_ * D_;
  const u16* Kp = kb + (size_t)bh * T_ * D_;
  const u16* Vp = vtb + (size_t)bh * D_ * T_;
  int qr0 = bq * 128 + wave * 16;  // this wave's q-row base

  // K staging: 16 rows/wave, 2 calls of 8 rows; 8 lanes/row, chunk pre-swizzled
  int rK = lane >> 3;
  int cK = ((lane & 7) ^ rK) * 8;
  const u16* gk0 = Kp + (size_t)(wave * 16 + rK) * D_ + cK;
  const u16* gk1 = gk0 + (size_t)8 * D_;
  // V staging: 8 d-rows/wave (256B each), 2 calls of 4 rows; 16 lanes/row
  int rV = lane >> 4;
  int cV = (lane & 15) ^ rV;  // call0 source chunk16; call1 = cV^4 (row&7 += 4)
  const u16* gv0 = Vp + (size_t)(wave * 8 + rV) * T_ + cV * 8;
  const u16* gv1 = Vp + (size_t)(wave * 8 + 4 + rV) * T_ + (cV ^ 4) * 8;

  // read-side swizzled chunk offsets (u16 units), constant per lane
  int koff0 = ((quad ^ (lr & 7)) << 3);
  int koff1 = (((4 | quad) ^ (lr & 7)) << 3);
  int lsw = lr & 7;

  // Q fragment as MFMA B-operand: B[n=q][k=d] (from global, unswizzled)
  bfrag8 qf[2];
#pragma unroll
  for (int ks = 0; ks < 2; ks++)
    qf[ks] = *(const bfrag8*)(Q + (size_t)(qr0 + lr) * D_ + ks * 32 + quad * 8);

  f32x4 zero = {0.f, 0.f, 0.f, 0.f};
  f32x4 o[4];
#pragma unroll
  for (int nn = 0; nn < 4; nn++) o[nn] = zero;
  float ps0 = 0.f, ps1 = 0.f, ps2 = 0.f, ps3 = 0.f;

  int nkt = bq + 1;                  // kv 128-tiles
  int wlast = 2 * bq + (wave >> 2);  // this wave's causal last SUBTILE (64-granule)
  int qloc = (wave & 3) * 16 + lr;   // q-pos within last subtile

  // prologue: stage kv-tile 0 (4 calls/thread)
  load_lds16(gk0, &Ks[0][(wave * 16) * 64]);
  load_lds16(gk1, &Ks[0][(wave * 16 + 8) * 64]);
  load_lds16(gv0, &Vt[0][(wave * 8) * 128]);
  load_lds16(gv1, &Vt[0][(wave * 8 + 4) * 128]);

  int buf = 0;
  for (int kt = 0; kt < nkt; kt++) {
    __syncthreads();  // drains tile-kt loads (issued one compute phase ago)
    if (kt + 1 < nkt) {
      int tb = (kt + 1) * 128;
      load_lds16(gk0 + (size_t)tb * D_, &Ks[buf ^ 1][(wave * 16) * 64]);
      load_lds16(gk1 + (size_t)tb * D_, &Ks[buf ^ 1][(wave * 16 + 8) * 64]);
      load_lds16(gv0 + tb, &Vt[buf ^ 1][(wave * 8) * 128]);
      load_lds16(gv1 + tb, &Vt[buf ^ 1][(wave * 8 + 4) * 128]);
    }
    const u16* ks_ = Ks[buf];
    const u16* vt_ = Vt[buf];
#pragma unroll
    for (int h = 0; h < 2; h++) {
      int st = 2 * kt + h;
      if (st <= wlast) {  // wave-uniform
        // S^T = K Q^T : 64 kv-rows x 16 q-cols (A=K-frag swizzled, B=Q-frag)
        f32x4 s[4];
#pragma unroll
        for (int j = 0; j < 4; j++) s[j] = zero;
#pragma unroll
        for (int j = 0; j < 4; j++) {
          const u16* kr = &ks_[(h * 64 + j * 16 + lr) * 64];
          bfrag8 kf0 = *(const bfrag8*)(kr + koff0);
          bfrag8 kf1 = *(const bfrag8*)(kr + koff1);
          s[j] = MFMA_BF16(kf0, qf[0], s[j]);
          s[j] = MFMA_BF16(kf1, qf[1], s[j]);
        }

        // P = exp2(S) + manual pair-pack + 4-way psum; Pst chunk16-XOR swizzled
        bool edge = (st == wlast);  // wave-uniform
#pragma unroll
        for (int j = 0; j < 4; j++) {
          float p[4];
#pragma unroll
          for (int r = 0; r < 4; r++) {
            float e = exp2_fast(s[j][r]);
            if (edge) {
              int kvloc = j * 16 + quad * 4 + r;
              e = (kvloc <= qloc) ? e : 0.f;
            }
            p[r] = e;
          }
          ps0 += p[0];
          ps1 += p[1];
          ps2 += p[2];
          ps3 += p[3];
          u32 u0 = __builtin_bit_cast(u32, p[0]) + 0x8000u;
          u32 u1 = __builtin_bit_cast(u32, p[1]) + 0x8000u;
          u32 u2 = __builtin_bit_cast(u32, p[2]) + 0x8000u;
          u32 u3 = __builtin_bit_cast(u32, p[3]) + 0x8000u;
          uint2 pk;
          pk.x = (u0 >> 16) | (u1 & 0xffff0000u);
          pk.y = (u2 >> 16) | (u3 & 0xffff0000u);
          // logical 16B-chunk (2j + quad>>1), half (quad&1), stored at chunk^lsw
          *(uint2*)&Pst[wave][lr * 64 + (((2 * j + (quad >> 1)) ^ lsw) << 3) +
                              ((quad & 1) << 2)] = pk;
        }

        // O += P V : A = P[q][t] (b128, swizzled), B = V^T[d][t] (swizzled, 128-wide)
#pragma unroll
        for (int ks = 0; ks < 2; ks++) {
          bfrag8 pf = *(const bfrag8*)&Pst[wave][lr * 64 + (((4 * ks + quad) ^ lsw) << 3)];
#pragma unroll
          for (int nn = 0; nn < 4; nn++) {
            int vko = ((8 * h + 4 * ks + quad) ^ lsw) << 3;
            bfrag8 vf = *(const bfrag8*)&vt_[(nn * 16 + lr) * 128 + vko];
            o[nn] = MFMA_BF16(pf, vf, o[nn]);
          }
        }
      }
    }
    buf ^= 1;
  }

  // total row-sum: reduce over the 4 quads
  float l = (ps0 + ps1) + (ps2 + ps3);
  l += __shfl_xor(l, 16, 64);
  l += __shfl_xor(l, 32, 64);
  float linv = 1.0f / l;

#pragma unroll
  for (int r = 0; r < 4; r++) {
    float lrec = __shfl(linv, quad * 4 + r, 64);
    int row = qr0 + quad * 4 + r;
#pragma unroll
    for (int nn = 0; nn < 4; nn++)
      ob[(size_t)(b * T_ + row) * C_ + h2 * 64 + nn * 16 + lr] = f2bf(o[nn][r] * lrec);
  }
}

// -------- GEMM 2: out(f32) = A(4096x1024)bf16 @ WT(1024x1024)bf16 + bias(f32).
// 64x128 tile (grid 512), BK=64 + chunk-XOR swizzle (r7 exact, FROZEN). --------
__global__ __launch_bounds__(256) void gemm_proj(const u16* __restrict__ A,
                                                 const u16* __restrict__ WT,
                                                 const float* __restrict__ bias,
                                                 float* __restrict__ out) {
  const int K = C_;
  __shared__ __align__(16) u16 As[2][64 * 64];   // 16 KB
  __shared__ __align__(16) u16 Bs[2][128 * 64];  // 32 KB
  int tid = threadIdx.x;
  int lane = tid & 63, wave = tid >> 6;
  int quad = lane >> 4, lr = lane & 15;
  int m0 = blockIdx.y * 64, n0 = blockIdx.x * 128;
  int wcol = wave * 32;
  int srow = lane >> 3;
  int schunk = (lane & 7) ^ srow;  // pre-swizzled global source chunk

  int koff0 = ((quad ^ (lr & 7)) << 3);
  int koff1 = (((4 | quad) ^ (lr & 7)) << 3);

  f32x4 zero = {0.f, 0.f, 0.f, 0.f};
  f32x4 acc[4][2];
#pragma unroll
  for (int i = 0; i < 4; i++)
#pragma unroll
    for (int j = 0; j < 2; j++) acc[i][j] = zero;

  const u16* ga = A + (size_t)(m0 + wave * 16 + srow) * K + schunk * 8;
  const u16* gb = WT + (size_t)(n0 + wave * 32 + srow) * K + schunk * 8;

  // prologue: A rows wave*16 + {0,8}; B rows wave*32 + {0,8,16,24}
  load_lds16(ga, &As[0][(wave * 16) * 64]);
  load_lds16(ga + (size_t)8 * K, &As[0][(wave * 16 + 8) * 64]);
#pragma unroll
  for (int l = 0; l < 4; l++)
    load_lds16(gb + (size_t)(l * 8) * K, &Bs[0][(wave * 32 + l * 8) * 64]);

  int buf = 0;
  for (int k0 = 0; k0 < K; k0 += 64) {
    __syncthreads();
    if (k0 + 64 < K) {
      load_lds16(ga + k0 + 64, &As[buf ^ 1][(wave * 16) * 64]);
      load_lds16(ga + (size_t)8 * K + k0 + 64, &As[buf ^ 1][(wave * 16 + 8) * 64]);
#pragma unroll
      for (int l = 0; l < 4; l++)
        load_lds16(gb + (size_t)(l * 8) * K + k0 + 64, &Bs[buf ^ 1][(wave * 32 + l * 8) * 64]);
    }
    bfrag8 af[4][2], bf[2][2];
#pragma unroll
    for (int i = 0; i < 4; i++) {
      const u16* ar = &As[buf][(i * 16 + lr) * 64];
      af[i][0] = *(const bfrag8*)(ar + koff0);
      af[i][1] = *(const bfrag8*)(ar + koff1);
    }
#pragma unroll
    for (int j = 0; j < 2; j++) {
      const u16* br = &Bs[buf][(wcol + j * 16 + lr) * 64];
      bf[j][0] = *(const bfrag8*)(br + koff0);
      bf[j][1] = *(const bfrag8*)(br + koff1);
    }
#pragma unroll
    for (int i = 0; i < 4; i++)
#pragma unroll
      for (int j = 0; j < 2; j++) {
        acc[i][j] = MFMA_BF16(af[i][0], bf[j][0], acc[i][j]);
        acc[i][j] = MFMA_BF16(af[i][1], bf[j][1], acc[i][j]);
      }
    buf ^= 1;
  }

#pragma unroll
  for (int i = 0; i < 4; i++)
#pragma unroll
    for (int r = 0; r < 4; r++) {
      int m = m0 + i * 16 + quad * 4 + r;
#pragma unroll
      for (int j = 0; j < 2; j++) {
        int n = n0 + wcol + j * 16 + lr;
        out[(size_t)m * C_ + n] = acc[i][j][r] + bias[n];
      }
    }
}

extern "C" void kernel_launch(void* const* d_in, const int* in_sizes, int n_in,
                              void* d_out, int out_size, void* d_ws, size_t ws_size,
                              hipStream_t stream) {
  const float* x = (const float*)d_in[0];       // [4096,1024] f32
  const float* w_qkv = (const float*)d_in[1];   // [1024,3072] f32
  const float* w_proj = (const float*)d_in[2];  // [1024,1024] f32
  const float* b_proj = (const float*)d_in[3];  // [1024] f32

  char* w = (char*)d_ws;
  u16* xb = (u16*)(w + 256);                 // 4096*1024 bf16 (A for gemm_qkv)
  u16* regA = xb + (size_t)4096 * 1024;      // max(wqkvT, abuf)
  u16* wqkvT = regA;                         // 3072*1024 (dead after gemm_qkv)
  u16* abuf = regA;                          // 4096*1024 (written by attn)
  u16* wprojT = regA + (size_t)4096 * 1024;  // 1024*1024
  u16* qbuf = wprojT + (size_t)1024 * 1024;
  u16* kbuf = qbuf + (size_t)B_ * H_ * T_ * D_;
  u16* vtb = kbuf + (size_t)B_ * H_ * T_ * D_;  // V^T [bh][d][t] (written by gemm_qkv)

  prep<<<3072, 256, 0, stream>>>(x, xb, w_qkv, wqkvT, w_proj, wprojT);
  gemm_qkv_rope<<<dim3(NQKV_ / 128, (B_ * T_) / 128), 256, 0, stream>>>(xb, wqkvT, qbuf, kbuf, vtb);
  attn_k<<<512, 512, 0, stream>>>(qbuf, kbuf, vtb, abuf);
  gemm_proj<<<dim3(C_ / 128, (B_ * T_) / 64), 256, 0, stream>>>(abuf, wprojT, b_proj, (float*)d_out);
}

// Round 13
// 178.913 us; speedup vs baseline: 1.1309x; 1.0080x over previous
//
#include <hip/hip_runtime.h>
#include <math.h>

typedef unsigned short u16;
typedef unsigned int u32;
typedef __bf16 bfrag8 __attribute__((ext_vector_type(8)));
typedef float f32x4 __attribute__((ext_vector_type(4)));

#define B_ 2
#define T_ 2048
#define H_ 16
#define D_ 64
#define C_ 1024
#define NQKV_ 3072

#define MFMA_BF16(a, b, c) __builtin_amdgcn_mfma_f32_16x16x32_bf16((a), (b), (c), 0, 0, 0)

__device__ __forceinline__ u16 f2bf(float f) {
  u32 u = __builtin_bit_cast(u32, f);
  u += 0x7fffu + ((u >> 16) & 1u);  // RNE
  return (u16)(u >> 16);
}

// exp2 via the target builtin: single v_exp_f32 with compiler-managed TRANS hazard
__device__ __forceinline__ float exp2_fast(float x) {
#if __has_builtin(__builtin_amdgcn_exp2f)
  return __builtin_amdgcn_exp2f(x);
#else
  return __expf(x * 0.6931471805599453f);
#endif
}

// async global->LDS, 16B/lane; lds dest = wave-uniform base + lane*16
__device__ __forceinline__ void load_lds16(const u16* gp, u16* lp) {
  __builtin_amdgcn_global_load_lds(
      (const __attribute__((address_space(1))) u32*)(const void*)gp,
      (__attribute__((address_space(3))) u32*)(void*)lp, 16, 0, 0);
}

// -------- fused prep: convert x (f32->bf16) + transpose both weights. --------
__global__ __launch_bounds__(256) void prep(const float* __restrict__ x,
                                            u16* __restrict__ xb,
                                            const float* __restrict__ wqkv,
                                            u16* __restrict__ wqkvT,
                                            const float* __restrict__ wproj,
                                            u16* __restrict__ wprojT) {
  int bid = blockIdx.x;
  int tid = threadIdx.x;
  __shared__ u16 tile[64][65];
  if (bid < 2048) {
    size_t i = ((size_t)bid * 256 + tid) * 8;
    const float* s = x + i;
    float4 a = *(const float4*)s, b = *(const float4*)(s + 4);
    union { uint4 v; u16 h[8]; } t;
    t.h[0] = f2bf(a.x); t.h[1] = f2bf(a.y); t.h[2] = f2bf(a.z); t.h[3] = f2bf(a.w);
    t.h[4] = f2bf(b.x); t.h[5] = f2bf(b.y); t.h[6] = f2bf(b.z); t.h[7] = f2bf(b.w);
    *(uint4*)(xb + i) = t.v;
    return;
  }
  const float* src;
  u16* dst;
  int N, bx, by;
  if (bid < 2816) {
    int rel = bid - 2048;
    src = wqkv; dst = wqkvT; N = NQKV_;
    bx = (rel % 48) * 64; by = (rel / 48) * 64;
  } else {
    int rel = bid - 2816;
    src = wproj; dst = wprojT; N = C_;
    bx = (rel & 15) * 64; by = (rel >> 4) * 64;
  }
  for (int idx = tid; idx < 4096; idx += 256) {
    int r = idx >> 6, c = idx & 63;
    tile[r][c] = f2bf(src[(size_t)(by + r) * N + bx + c]);
  }
  __syncthreads();
  for (int idx = tid; idx < 4096; idx += 256) {
    int r = idx >> 6, c = idx & 63;
    dst[(size_t)(bx + r) * C_ + by + c] = tile[c][r];
  }
}

// -------- GEMM 1: qkv = X(4096x1024)bf16 @ WT(3072x1024)bf16, RoPE epilogue.
// r13: 128x192 tile, 6 waves (384 thr, 2Mx3N, each wave 64x64 = head-aligned),
// grid 16x32 = 512 blocks = EXACTLY 2 blocks/CU (80KB LDS) -> one full round,
// no half-empty tail (old 768-block grid ran 1.5 rounds; solo tail blocks can't
// saturate a CU). Inner loop = r5-proven dbuf BK=64 chunk-XOR swizzle, UNCHANGED.
// q pre-scaled by 0.125*log2e: attn computes P = exp2(S) directly. --------
__global__ __launch_bounds__(384) void gemm_qkv_rope(const u16* __restrict__ X,
                                                     const u16* __restrict__ WT,
                                                     u16* __restrict__ qb,
                                                     u16* __restrict__ kb,
                                                     u16* __restrict__ vtb) {
  const int K = C_;
  __shared__ __align__(16) u16 As[2][128 * 64];  // 32 KB
  __shared__ __align__(16) u16 Bs[2][192 * 64];  // 48 KB
  int tid = threadIdx.x;
  int lane = tid & 63, wave = tid >> 6;  // 6 waves
  int quad = lane >> 4, lr = lane & 15;
  int m0 = blockIdx.y * 128, n0 = blockIdx.x * 192;
  int wm = wave / 3, wn = wave % 3;
  int wrow = wm * 64, wcol = wn * 64;
  int srow = lane >> 3;
  int schunk = (lane & 7) ^ srow;  // pre-swizzled global source chunk

  // read-side swizzled chunk offsets (u16 units): logical chunk (ks*4+quad) ^ (row&7)
  int koff0 = ((quad ^ (lr & 7)) << 3);
  int koff1 = (((4 | quad) ^ (lr & 7)) << 3);

  f32x4 zero = {0.f, 0.f, 0.f, 0.f};
  f32x4 acc[4][4];
#pragma unroll
  for (int i = 0; i < 4; i++)
#pragma unroll
    for (int j = 0; j < 4; j++) acc[i][j] = zero;

  // staging assignment: waves 0,1 -> A (8 rowgroups of 8 each);
  // waves 2..5 -> B (6 rowgroups of 8 each). All staged rows &7 == srow.
  bool isA = wave < 2;
  const u16* gsrc;
  u16* ldsbase0;
  int ncalls, rgbase;
  if (isA) {
    rgbase = wave * 64;  // first row this wave stages
    gsrc = X + (size_t)(m0 + rgbase + srow) * K + schunk * 8;
    ncalls = 8;
  } else {
    rgbase = (wave - 2) * 48;
    gsrc = WT + (size_t)(n0 + rgbase + srow) * K + schunk * 8;
    ncalls = 6;
  }

  // prologue: stage tile 0
  for (int l = 0; l < ncalls; l++) {
    u16* d = isA ? &As[0][(rgbase + l * 8) * 64] : &Bs[0][(rgbase + l * 8) * 64];
    load_lds16(gsrc + (size_t)(l * 8) * K, d);
  }

  int buf = 0;
  for (int k0 = 0; k0 < K; k0 += 64) {
    __syncthreads();  // drains tile-k0 loads (issued one compute phase ago)
    if (k0 + 64 < K) {
      for (int l = 0; l < ncalls; l++) {
        u16* d = isA ? &As[buf ^ 1][(rgbase + l * 8) * 64]
                     : &Bs[buf ^ 1][(rgbase + l * 8) * 64];
        load_lds16(gsrc + (size_t)(l * 8) * K + k0 + 64, d);
      }
    }
    bfrag8 af[4][2], bf[4][2];
#pragma unroll
    for (int i = 0; i < 4; i++) {
      const u16* ar = &As[buf][(wrow + i * 16 + lr) * 64];
      af[i][0] = *(const bfrag8*)(ar + koff0);
      af[i][1] = *(const bfrag8*)(ar + koff1);
    }
#pragma unroll
    for (int j = 0; j < 4; j++) {
      const u16* br = &Bs[buf][(wcol + j * 16 + lr) * 64];
      bf[j][0] = *(const bfrag8*)(br + koff0);
      bf[j][1] = *(const bfrag8*)(br + koff1);
    }
#pragma unroll
    for (int i = 0; i < 4; i++)
#pragma unroll
      for (int j = 0; j < 4; j++) {
        acc[i][j] = MFMA_BF16(af[i][0], bf[j][0], acc[i][j]);
        acc[i][j] = MFMA_BF16(af[i][1], bf[j][1], acc[i][j]);
      }
    buf ^= 1;
  }

  int colbase = n0 + wcol;          // multiple of 64 -> single head per wave
  int which = colbase >> 10;        // 0=q 1=k 2=v (wave-uniform)
  int h = (colbase & 1023) >> 6;
  if (which < 2) {
    u16* dst = which == 0 ? qb : kb;
    // q pre-scaled by 1/8 * log2(e): attn computes P = exp2(S) directly
    float sc0 = (which == 0) ? 0.18033688011112042f : 1.0f;
    float fr0 = __expf(-0.28782313662425574f * (float)lr);        // ln(10000)/32
    float fr1 = __expf(-0.28782313662425574f * (float)(16 + lr));
#pragma unroll
    for (int i = 0; i < 4; i++) {
#pragma unroll
      for (int r = 0; r < 4; r++) {
        int m = m0 + wrow + i * 16 + quad * 4 + r;
        int b = m >> 11, tt = m & 2047;
        size_t base = ((size_t)(b * H_ + h) * T_ + tt) * D_;
        float sn, cs;
        __sincosf((float)tt * fr0, &sn, &cs);
        dst[base + lr] = f2bf((acc[i][0][r] * cs - acc[i][2][r] * sn) * sc0);
        dst[base + lr + 32] = f2bf((acc[i][0][r] * sn + acc[i][2][r] * cs) * sc0);
        __sincosf((float)tt * fr1, &sn, &cs);
        dst[base + 16 + lr] = f2bf((acc[i][1][r] * cs - acc[i][3][r] * sn) * sc0);
        dst[base + 48 + lr] = f2bf((acc[i][1][r] * sn + acc[i][3][r] * cs) * sc0);
      }
    }
  } else {
    // V: write transposed [bh][d][t]; lane holds 4 consecutive t per (i,j) -> 8B store
#pragma unroll
    for (int i = 0; i < 4; i++) {
      int mb = m0 + wrow + i * 16 + quad * 4;  // 4 consecutive t from here (same b)
      int b = mb >> 11, tt = mb & 2047;
      u16* vb = vtb + ((size_t)(b * H_ + h) * D_) * T_ + tt;
#pragma unroll
      for (int j = 0; j < 4; j++) {
        union { uint2 v; u16 hh[4]; } pk;
#pragma unroll
        for (int r = 0; r < 4; r++) pk.hh[r] = f2bf(acc[i][j][r]);
        *(uint2*)(vb + (size_t)(j * 16 + lr) * T_) = pk.v;
      }
    }
  }
}

// -------- attention: causal, S^T formulation, q-tile 128 (8 waves, 512 thr,
// 16 q-rows/wave). kv staging tile 128 (2 compute subtiles of 64 per barrier);
// Pst chunk16-XOR swizzled; 80KB LDS = 2 blocks/CU. (r12 exact, FROZEN) ----
__global__ __launch_bounds__(512) void attn_k(const u16* __restrict__ qb,
                                              const u16* __restrict__ kb,
                                              const u16* __restrict__ vtb,
                                              u16* __restrict__ ob) {
  __shared__ __align__(16) u16 Ks[2][128 * 64];  // [t][chunk^(t&7)]   16 KB each
  __shared__ __align__(16) u16 Vt[2][64 * 128];  // [d][chunk16^(d&7)] 16 KB each
  __shared__ __align__(16) u16 Pst[8][16 * 64];  // per-wave P, chunk16-XOR swizzled
  int tid = threadIdx.x;
  int lane = tid & 63, wave = tid >> 6;
  int quad = lane >> 4, lr = lane & 15;
  int i = blockIdx.x;
  int bq = 15 - (i >> 5);  // heavy blocks dispatched first (16 q-blocks of 128)
  int bh = i & 31;
  int b = bh >> 4, h2 = bh & 15;
  const u16* Q = qb + (size_t)bh * T_ * D_;
  const u16* Kp = kb + (size_t)bh * T_ * D_;
  const u16* Vp = vtb + (size_t)bh * D_ * T_;
  int qr0 = bq * 128 + wave * 16;  // this wave's q-row base

  // K staging: 16 rows/wave, 2 calls of 8 rows; 8 lanes/row, chunk pre-swizzled
  int rK = lane >> 3;
  int cK = ((lane & 7) ^ rK) * 8;
  const u16* gk0 = Kp + (size_t)(wave * 16 + rK) * D_ + cK;
  const u16* gk1 = gk0 + (size_t)8 * D_;
  // V staging: 8 d-rows/wave (256B each), 2 calls of 4 rows; 16 lanes/row
  int rV = lane >> 4;
  int cV = (lane & 15) ^ rV;  // call0 source chunk16; call1 = cV^4 (row&7 += 4)
  const u16* gv0 = Vp + (size_t)(wave * 8 + rV) * T_ + cV * 8;
  const u16* gv1 = Vp + (size_t)(wave * 8 + 4 + rV) * T_ + (cV ^ 4) * 8;

  // read-side swizzled chunk offsets (u16 units), constant per lane
  int koff0 = ((quad ^ (lr & 7)) << 3);
  int koff1 = (((4 | quad) ^ (lr & 7)) << 3);
  int lsw = lr & 7;

  // Q fragment as MFMA B-operand: B[n=q][k=d] (from global, unswizzled)
  bfrag8 qf[2];
#pragma unroll
  for (int ks = 0; ks < 2; ks++)
    qf[ks] = *(const bfrag8*)(Q + (size_t)(qr0 + lr) * D_ + ks * 32 + quad * 8);

  f32x4 zero = {0.f, 0.f, 0.f, 0.f};
  f32x4 o[4];
#pragma unroll
  for (int nn = 0; nn < 4; nn++) o[nn] = zero;
  float ps0 = 0.f, ps1 = 0.f, ps2 = 0.f, ps3 = 0.f;

  int nkt = bq + 1;                  // kv 128-tiles
  int wlast = 2 * bq + (wave >> 2);  // this wave's causal last SUBTILE (64-granule)
  int qloc = (wave & 3) * 16 + lr;   // q-pos within last subtile

  // prologue: stage kv-tile 0 (4 calls/thread)
  load_lds16(gk0, &Ks[0][(wave * 16) * 64]);
  load_lds16(gk1, &Ks[0][(wave * 16 + 8) * 64]);
  load_lds16(gv0, &Vt[0][(wave * 8) * 128]);
  load_lds16(gv1, &Vt[0][(wave * 8 + 4) * 128]);

  int buf = 0;
  for (int kt = 0; kt < nkt; kt++) {
    __syncthreads();  // drains tile-kt loads (issued one compute phase ago)
    if (kt + 1 < nkt) {
      int tb = (kt + 1) * 128;
      load_lds16(gk0 + (size_t)tb * D_, &Ks[buf ^ 1][(wave * 16) * 64]);
      load_lds16(gk1 + (size_t)tb * D_, &Ks[buf ^ 1][(wave * 16 + 8) * 64]);
      load_lds16(gv0 + tb, &Vt[buf ^ 1][(wave * 8) * 128]);
      load_lds16(gv1 + tb, &Vt[buf ^ 1][(wave * 8 + 4) * 128]);
    }
    const u16* ks_ = Ks[buf];
    const u16* vt_ = Vt[buf];
#pragma unroll
    for (int h = 0; h < 2; h++) {
      int st = 2 * kt + h;
      if (st <= wlast) {  // wave-uniform
        // S^T = K Q^T : 64 kv-rows x 16 q-cols (A=K-frag swizzled, B=Q-frag)
        f32x4 s[4];
#pragma unroll
        for (int j = 0; j < 4; j++) s[j] = zero;
#pragma unroll
        for (int j = 0; j < 4; j++) {
          const u16* kr = &ks_[(h * 64 + j * 16 + lr) * 64];
          bfrag8 kf0 = *(const bfrag8*)(kr + koff0);
          bfrag8 kf1 = *(const bfrag8*)(kr + koff1);
          s[j] = MFMA_BF16(kf0, qf[0], s[j]);
          s[j] = MFMA_BF16(kf1, qf[1], s[j]);
        }

        // P = exp2(S) + manual pair-pack + 4-way psum; Pst chunk16-XOR swizzled
        bool edge = (st == wlast);  // wave-uniform
#pragma unroll
        for (int j = 0; j < 4; j++) {
          float p[4];
#pragma unroll
          for (int r = 0; r < 4; r++) {
            float e = exp2_fast(s[j][r]);
            if (edge) {
              int kvloc = j * 16 + quad * 4 + r;
              e = (kvloc <= qloc) ? e : 0.f;
            }
            p[r] = e;
          }
          ps0 += p[0];
          ps1 += p[1];
          ps2 += p[2];
          ps3 += p[3];
          u32 u0 = __builtin_bit_cast(u32, p[0]) + 0x8000u;
          u32 u1 = __builtin_bit_cast(u32, p[1]) + 0x8000u;
          u32 u2 = __builtin_bit_cast(u32, p[2]) + 0x8000u;
          u32 u3 = __builtin_bit_cast(u32, p[3]) + 0x8000u;
          uint2 pk;
          pk.x = (u0 >> 16) | (u1 & 0xffff0000u);
          pk.y = (u2 >> 16) | (u3 & 0xffff0000u);
          // logical 16B-chunk (2j + quad>>1), half (quad&1), stored at chunk^lsw
          *(uint2*)&Pst[wave][lr * 64 + (((2 * j + (quad >> 1)) ^ lsw) << 3) +
                              ((quad & 1) << 2)] = pk;
        }

        // O += P V : A = P[q][t] (b128, swizzled), B = V^T[d][t] (swizzled, 128-wide)
#pragma unroll
        for (int ks = 0; ks < 2; ks++) {
          bfrag8 pf = *(const bfrag8*)&Pst[wave][lr * 64 + (((4 * ks + quad) ^ lsw) << 3)];
#pragma unroll
          for (int nn = 0; nn < 4; nn++) {
            int vko = ((8 * h + 4 * ks + quad) ^ lsw) << 3;
            bfrag8 vf = *(const bfrag8*)&vt_[(nn * 16 + lr) * 128 + vko];
            o[nn] = MFMA_BF16(pf, vf, o[nn]);
          }
        }
      }
    }
    buf ^= 1;
  }

  // total row-sum: reduce over the 4 quads
  float l = (ps0 + ps1) + (ps2 + ps3);
  l += __shfl_xor(l, 16, 64);
  l += __shfl_xor(l, 32, 64);
  float linv = 1.0f / l;

#pragma unroll
  for (int r = 0; r < 4; r++) {
    float lrec = __shfl(linv, quad * 4 + r, 64);
    int row = qr0 + quad * 4 + r;
#pragma unroll
    for (int nn = 0; nn < 4; nn++)
      ob[(size_t)(b * T_ + row) * C_ + h2 * 64 + nn * 16 + lr] = f2bf(o[nn][r] * lrec);
  }
}

// -------- GEMM 2: out(f32) = A(4096x1024)bf16 @ WT(1024x1024)bf16 + bias(f32).
// 64x128 tile (grid 512), BK=64 + chunk-XOR swizzle (r7 exact, FROZEN). --------
__global__ __launch_bounds__(256) void gemm_proj(const u16* __restrict__ A,
                                                 const u16* __restrict__ WT,
                                                 const float* __restrict__ bias,
                                                 float* __restrict__ out) {
  const int K = C_;
  __shared__ __align__(16) u16 As[2][64 * 64];   // 16 KB
  __shared__ __align__(16) u16 Bs[2][128 * 64];  // 32 KB
  int tid = threadIdx.x;
  int lane = tid & 63, wave = tid >> 6;
  int quad = lane >> 4, lr = lane & 15;
  int m0 = blockIdx.y * 64, n0 = blockIdx.x * 128;
  int wcol = wave * 32;
  int srow = lane >> 3;
  int schunk = (lane & 7) ^ srow;  // pre-swizzled global source chunk

  int koff0 = ((quad ^ (lr & 7)) << 3);
  int koff1 = (((4 | quad) ^ (lr & 7)) << 3);

  f32x4 zero = {0.f, 0.f, 0.f, 0.f};
  f32x4 acc[4][2];
#pragma unroll
  for (int i = 0; i < 4; i++)
#pragma unroll
    for (int j = 0; j < 2; j++) acc[i][j] = zero;

  const u16* ga = A + (size_t)(m0 + wave * 16 + srow) * K + schunk * 8;
  const u16* gb = WT + (size_t)(n0 + wave * 32 + srow) * K + schunk * 8;

  // prologue: A rows wave*16 + {0,8}; B rows wave*32 + {0,8,16,24}
  load_lds16(ga, &As[0][(wave * 16) * 64]);
  load_lds16(ga + (size_t)8 * K, &As[0][(wave * 16 + 8) * 64]);
#pragma unroll
  for (int l = 0; l < 4; l++)
    load_lds16(gb + (size_t)(l * 8) * K, &Bs[0][(wave * 32 + l * 8) * 64]);

  int buf = 0;
  for (int k0 = 0; k0 < K; k0 += 64) {
    __syncthreads();
    if (k0 + 64 < K) {
      load_lds16(ga + k0 + 64, &As[buf ^ 1][(wave * 16) * 64]);
      load_lds16(ga + (size_t)8 * K + k0 + 64, &As[buf ^ 1][(wave * 16 + 8) * 64]);
#pragma unroll
      for (int l = 0; l < 4; l++)
        load_lds16(gb + (size_t)(l * 8) * K + k0 + 64, &Bs[buf ^ 1][(wave * 32 + l * 8) * 64]);
    }
    bfrag8 af[4][2], bf[2][2];
#pragma unroll
    for (int i = 0; i < 4; i++) {
      const u16* ar = &As[buf][(i * 16 + lr) * 64];
      af[i][0] = *(const bfrag8*)(ar + koff0);
      af[i][1] = *(const bfrag8*)(ar + koff1);
    }
#pragma unroll
    for (int j = 0; j < 2; j++) {
      const u16* br = &Bs[buf][(wcol + j * 16 + lr) * 64];
      bf[j][0] = *(const bfrag8*)(br + koff0);
      bf[j][1] = *(const bfrag8*)(br + koff1);
    }
#pragma unroll
    for (int i = 0; i < 4; i++)
#pragma unroll
      for (int j = 0; j < 2; j++) {
        acc[i][j] = MFMA_BF16(af[i][0], bf[j][0], acc[i][j]);
        acc[i][j] = MFMA_BF16(af[i][1], bf[j][1], acc[i][j]);
      }
    buf ^= 1;
  }

#pragma unroll
  for (int i = 0; i < 4; i++)
#pragma unroll
    for (int r = 0; r < 4; r++) {
      int m = m0 + i * 16 + quad * 4 + r;
#pragma unroll
      for (int j = 0; j < 2; j++) {
        int n = n0 + wcol + j * 16 + lr;
        out[(size_t)m * C_ + n] = acc[i][j][r] + bias[n];
      }
    }
}

extern "C" void kernel_launch(void* const* d_in, const int* in_sizes, int n_in,
                              void* d_out, int out_size, void* d_ws, size_t ws_size,
                              hipStream_t stream) {
  const float* x = (const float*)d_in[0];       // [4096,1024] f32
  const float* w_qkv = (const float*)d_in[1];   // [1024,3072] f32
  const float* w_proj = (const float*)d_in[2];  // [1024,1024] f32
  const float* b_proj = (const float*)d_in[3];  // [1024] f32

  char* w = (char*)d_ws;
  u16* xb = (u16*)(w + 256);                 // 4096*1024 bf16 (A for gemm_qkv)
  u16* regA = xb + (size_t)4096 * 1024;      // max(wqkvT, abuf)
  u16* wqkvT = regA;                         // 3072*1024 (dead after gemm_qkv)
  u16* abuf = regA;                          // 4096*1024 (written by attn)
  u16* wprojT = regA + (size_t)4096 * 1024;  // 1024*1024
  u16* qbuf = wprojT + (size_t)1024 * 1024;
  u16* kbuf = qbuf + (size_t)B_ * H_ * T_ * D_;
  u16* vtb = kbuf + (size_t)B_ * H_ * T_ * D_;  // V^T [bh][d][t] (written by gemm_qkv)

  prep<<<3072, 256, 0, stream>>>(x, xb, w_qkv, wqkvT, w_proj, wprojT);
  gemm_qkv_rope<<<dim3(NQKV_ / 192, (B_ * T_) / 128), 384, 0, stream>>>(xb, wqkvT, qbuf, kbuf, vtb);
  attn_k<<<512, 512, 0, stream>>>(qbuf, kbuf, vtb, abuf);
  gemm_proj<<<dim3(C_ / 128, (B_ * T_) / 64), 256, 0, stream>>>(abuf, wprojT, b_proj, (float*)d_out);
}